// Round 1
// 720.158 us; speedup vs baseline: 1.9255x; 1.9255x over previous
//
#include <hip/hip_runtime.h>
#include <stdint.h>

typedef unsigned short u16;
typedef unsigned int   u32;
typedef __attribute__((ext_vector_type(8))) short bf16x8;
typedef __attribute__((ext_vector_type(4))) float f32x4;
typedef __attribute__((ext_vector_type(4))) u32   u32x4;

static __device__ __forceinline__ float bf2f(u16 v){
  u32 u = ((u32)v) << 16;
  return __builtin_bit_cast(float, u);
}
static __device__ __forceinline__ u16 f2bf(float f){
  u32 u = __builtin_bit_cast(u32, f);
  return (u16)((u + 0x7fffu + ((u >> 16) & 1u)) >> 16);
}

#define MFMA16(a,b,c) __builtin_amdgcn_mfma_f32_16x16x32_bf16((a),(b),(c),0,0,0)

// async global->LDS, 16B per lane (emits global_load_lds_dwordx4)
typedef const __attribute__((address_space(1))) char glb_c;
typedef __attribute__((address_space(3))) char lds_c;
static __device__ __forceinline__ void gload_lds16(const void* g, void* l){
  __builtin_amdgcn_global_load_lds((glb_c*)g, (lds_c*)l, 16, 0, 0);
}

// Model dims
#define SEQN   2048
#define PROJD  8512
#define CONVD  4352
#define INTERD 4096
#define NST    128
#define QC     64
#define NCHUNK 32

// ---------------------------------------------------------------------------
// Input dtype detection (fp32 confirmed; kept for robustness).
__global__ __launch_bounds__(256) void detect_kernel(
    const void* __restrict__ hidden, u32* __restrict__ flag)
{
  __shared__ int cnt;
  if (threadIdx.x == 0) cnt = 0;
  __syncthreads();
  if (threadIdx.x < 128){
    u16 v = ((const u16*)hidden)[threadIdx.x * 2];
    int e = (v >> 7) & 0xFF;
    int plaus = (v == 0) || (e >= 0x70 && e <= 0x8F);
    atomicAdd(&cnt, plaus);
  }
  __syncthreads();
  if (threadIdx.x == 0) *flag = (cnt < 64) ? 1u : 0u;   // 1 = fp32 inputs
}

__global__ __launch_bounds__(256) void cvt_kernel(
    const void* __restrict__ src, u16* __restrict__ dst, int n,
    const u32* __restrict__ flag)
{
  bool isf32 = (*flag != 0);
  int stride = gridDim.x * 256;
  for (int i = blockIdx.x*256 + threadIdx.x; i < n; i += stride){
    if (isf32) dst[i] = f2bf(((const float*)src)[i]);
    else       dst[i] = ((const u16*)src)[i];
  }
}

// Convert + transpose weights: src [K][N] (fp32 or bf16) -> dst [Npad][K] bf16.
// Rows n >= N are zero-filled (pad for tile-exact GEMM).
__global__ __launch_bounds__(256) void cvt_transpose_kernel(
    const void* __restrict__ src, u16* __restrict__ dst,
    int K, int N, int Npad, const u32* __restrict__ flag)
{
  bool isf32 = (*flag != 0);
  __shared__ u16 tile[64][72];
  int n0 = blockIdx.x * 64, k0 = blockIdx.y * 64;
  int tid = threadIdx.x;
  int tr = tid >> 6;     // wave id 0..3
  int tc = tid & 63;
  #pragma unroll
  for (int i = 0; i < 16; i++){
    int k = i*4 + tr;
    int gk = k0 + k, gn = n0 + tc;
    float v = 0.f;
    if (gk < K && gn < N)
      v = isf32 ? ((const float*)src)[(size_t)gk*N + gn]
                : bf2f(((const u16*)src)[(size_t)gk*N + gn]);
    tile[k][tc] = f2bf(v);
  }
  __syncthreads();
  #pragma unroll
  for (int i = 0; i < 16; i++){
    int n = i*4 + tr;
    int gn = n0 + n;
    if (gn < Npad && (k0 + tc) < K)
      dst[(size_t)gn*K + k0 + tc] = tile[tc][n];
  }
}

__global__ __launch_bounds__(256) void cvt_small_kernel(
    const void* cw, const void* cb, const void* al, const void* dv,
    const void* db, const void* nw, u16* __restrict__ base,
    const u32* __restrict__ flag)
{
  bool isf32 = (*flag != 0);
  int idx = blockIdx.x*256 + threadIdx.x;   // 0 .. 26047
  if (idx >= 26048) return;
  const void* src; int off;
  if      (idx < 17408){ src = cw; off = idx;          }
  else if (idx < 21760){ src = cb; off = idx - 17408;  }
  else if (idx < 21824){ src = al; off = idx - 21760;  }
  else if (idx < 21888){ src = dv; off = idx - 21824;  }
  else if (idx < 21952){ src = db; off = idx - 21888;  }
  else                 { src = nw; off = idx - 21952;  }
  u16 v = isf32 ? f2bf(((const float*)src)[off]) : ((const u16*)src)[off];
  base[idx] = v;
}

// ---------------------------------------------------------------------------
// C = A[M,K] @ Bt[N,K]^T  (both row-major bf16, B pre-transposed), fp32 accum.
// m97 structure: global_load_lds width-16 staging, XOR-swizzled 128B LDS rows,
// 128x128 tile, BK=64, 4 waves x (64x64), conflict-free ds_read_b128.
// mode 0: bf16 C0.  mode 1: proj split -> z / xbcr / dtraw.  mode 2: fp32 CF.
// Requires: M%128==0, N%128==0 (pad), K%64==0, (gridDim.x*gridDim.y)%8==0.
__global__ __launch_bounds__(256) void gemm_kernel(
    const u16* __restrict__ A, const u16* __restrict__ Bt,
    u16* __restrict__ C0, u16* __restrict__ C1, u16* __restrict__ C2,
    float* __restrict__ CF,
    int M, int N, int K, int mode)
{
  __shared__ u16 sA[128*64];   // 16 KiB, 128B rows, source-swizzled
  __shared__ u16 sB[128*64];   // 16 KiB

  // bijective XCD swizzle (nwg % 8 == 0 for both GEMMs here)
  int nbx = gridDim.x;
  int nwg = nbx * gridDim.y;
  int bid = blockIdx.y * nbx + blockIdx.x;
  int swz = (bid & 7) * (nwg >> 3) + (bid >> 3);
  int m0 = (swz / nbx) * 128, n0 = (swz % nbx) * 128;

  int tid = threadIdx.x;
  int wave = tid >> 6, lane = tid & 63;
  int l15 = lane & 15, quad = lane >> 4;
  int wrow = (wave & 1) * 64, wcol = (wave >> 1) * 64;

  // staging geometry: thread t covers tile row (s*32 + t/8), 16B chunk (t%8);
  // source byte within the 128B row is XOR-swizzled so that a LINEAR LDS
  // write + swizzled ds_read is conflict-free (rule: both-sides-or-neither).
  int srow  = tid >> 3;                                   // 0..31
  int sboff = ((tid & 7) << 4) ^ ((srow & 7) << 4);       // byte in 128B row

  const char* Ag = (const char*)(A  + (size_t)(m0 + srow) * K);
  const char* Bg = (const char*)(Bt + (size_t)(n0 + srow) * K);
  char* sAw = (char*)sA + wave*8*128;   // wave-uniform LDS dest base
  char* sBw = (char*)sB + wave*8*128;

  f32x4 acc[4][4];
  #pragma unroll
  for (int i=0;i<4;i++)
    #pragma unroll
    for (int j=0;j<4;j++) acc[i][j] = (f32x4){0.f,0.f,0.f,0.f};

  const char* sAc = (const char*)sA;
  const char* sBc = (const char*)sB;
  int xorv = (l15 & 7) << 4;

  for (int k0 = 0; k0 < K; k0 += 64){
    __syncthreads();
    size_t kb = (size_t)k0*2 + sboff;
    #pragma unroll
    for (int s = 0; s < 4; s++){
      gload_lds16(Ag + (size_t)(s*32)*K*2 + kb, sAw + s*32*128);
      gload_lds16(Bg + (size_t)(s*32)*K*2 + kb, sBw + s*32*128);
    }
    __syncthreads();   // compiler inserts vmcnt(0) drain here
    #pragma unroll
    for (int kk2 = 0; kk2 < 2; kk2++){
      bf16x8 af[4], bfr[4];
      #pragma unroll
      for (int i=0;i<4;i++)
        af[i]  = *(const bf16x8*)(sAc + (wrow + i*16 + l15)*128
                                      + ((quad*16 + kk2*64) ^ xorv));
      #pragma unroll
      for (int j=0;j<4;j++)
        bfr[j] = *(const bf16x8*)(sBc + (wcol + j*16 + l15)*128
                                      + ((quad*16 + kk2*64) ^ xorv));
      #pragma unroll
      for (int i=0;i<4;i++)
        #pragma unroll
        for (int j=0;j<4;j++)
          acc[i][j] = MFMA16(af[i], bfr[j], acc[i][j]);
    }
  }

  #pragma unroll
  for (int j=0;j<4;j++){
    int col = n0 + wcol + j*16 + l15;
    #pragma unroll
    for (int i=0;i<4;i++){
      #pragma unroll
      for (int r=0;r<4;r++){
        int row = m0 + wrow + i*16 + quad*4 + r;
        float fv = acc[i][j][r];
        if (mode == 2){
          if (col < N) CF[(size_t)row*N + col] = fv;
        } else if (mode == 0){
          if (col < N) C0[(size_t)row*N + col] = f2bf(fv);
        } else {
          u16 v = f2bf(fv);
          if      (col < 4096) C0[(size_t)row*4096 + col] = v;
          else if (col < 8448) C1[(size_t)row*CONVD + (col - 4096)] = v;
          else if (col < 8512) C2[(size_t)row*64 + (col - 8448)] = v;
          // cols 8512..8575 are zero-padding, dropped
        }
      }
    }
  }
}

// ---------------------------------------------------------------------------
// Causal depthwise conv (K=4, left pad 3) + bias + silu; 0.5 mup folded.
__global__ __launch_bounds__(256) void conv_silu_kernel(
    const u16* __restrict__ xbcr, const u16* __restrict__ conv_w,
    const u16* __restrict__ conv_b, u16* __restrict__ xbc)
{
  int c  = blockIdx.x * 256 + threadIdx.x;   // 17*256 = 4352 exact
  int rl = blockIdx.y;
  int b = rl >> 11, l = rl & 2047;
  float w[4];
  #pragma unroll
  for (int k=0;k<4;k++) w[k] = 0.5f * bf2f(conv_w[c*4 + k]);
  float acc = bf2f(conv_b[c]);
  #pragma unroll
  for (int k=0;k<4;k++){
    int s = l + k - 3;
    if (s >= 0) acc += bf2f(xbcr[(size_t)(b*2048 + s)*CONVD + c]) * w[k];
  }
  float sig = 1.f / (1.f + __expf(-acc));
  xbc[(size_t)rl*CONVD + c] = f2bf(acc * sig);
}

// ---------------------------------------------------------------------------
// dt_soft = softplus(dtraw + dt_bias); ldA = dt_soft * (-exp(A_log)).
__global__ __launch_bounds__(256) void dt_kernel(
    const u16* __restrict__ dtraw, const u16* __restrict__ dt_bias,
    const u16* __restrict__ A_log, float* __restrict__ dt_soft,
    float* __restrict__ ldA)
{
  int idx = blockIdx.x * 256 + threadIdx.x;  // 4096*64
  int h = idx & 63;
  float x = bf2f(dtraw[idx]) + bf2f(dt_bias[h]);
  float sp = (x > 20.f) ? x : log1pf(expf(x));
  float A = -expf(bf2f(A_log[h]));
  dt_soft[idx] = sp;
  ldA[idx] = sp * A;
}

__global__ __launch_bounds__(256) void chunk_decay_kernel(
    const float* __restrict__ ldA, float* __restrict__ cdexp)
{
  int idx = blockIdx.x * 256 + threadIdx.x;  // 4096
  int q = idx & 31, bh = idx >> 5;
  int b = bh >> 6, h = bh & 63;
  float s = 0.f;
  int t0 = q * QC;
  for (int t = 0; t < QC; t++) s += ldA[(size_t)(b*2048 + t0 + t)*64 + h];
  cdexp[idx] = expf(s);
}

// ---------------------------------------------------------------------------
// SSD intra-chunk (validated in r4 bisection: matches exact scan).
#define SBS  136
#define SUTS 80
#define SMS  80
__global__ __launch_bounds__(256) void ssd_intra_kernel(
    const u16* __restrict__ xbc, const float* __restrict__ dt_soft,
    const float* __restrict__ ldA, u16* __restrict__ S,
    u16* __restrict__ y)
{
  int q = blockIdx.x, h = blockIdx.y, b = blockIdx.z;
  int bh = b*64 + h;
  int t0 = q * QC;
  int tid = threadIdx.x, wave = tid >> 6, lane = tid & 63;
  int l15 = lane & 15, quad = lane >> 4;

  __shared__ u16 sB [64*SBS];
  __shared__ u16 sCM[64*SBS];
  __shared__ u16 sBt[128*64];
  __shared__ u16 sUt[64*SUTS];
  __shared__ float sLa[64];
  __shared__ float sW[64];

  if (tid < 64){
    float v = ldA[(size_t)(b*2048 + t0 + tid)*64 + h];
    #pragma unroll
    for (int off = 1; off < 64; off <<= 1){
      float o = __shfl_up(v, off, 64);
      if (lane >= off) v += o;
    }
    sLa[tid] = v;
  }
  __syncthreads();
  float laE = sLa[63];
  if (tid < 64) sW[tid] = __expf(laE - sLa[tid]);
  __syncthreads();

  #pragma unroll
  for (int i = 0; i < 4; i++){
    int ch = i*256 + tid;
    int s = ch >> 4, nc = (ch & 15) * 8;
    const u16* src = xbc + (size_t)(b*2048 + t0 + s)*CONVD;
    u32x4 vb = *(const u32x4*)(src + 4096 + nc);
    u32x4 vc = *(const u32x4*)(src + 4224 + nc);
    *(u32x4*)(sB  + s*SBS + nc) = vb;
    *(u32x4*)(sCM + s*SBS + nc) = vc;
    float wdec = sW[s];
    const u16* pb = (const u16*)&vb;
    #pragma unroll
    for (int e = 0; e < 8; e++)
      sBt[(nc + e)*64 + s] = f2bf(bf2f(pb[e]) * wdec);
  }
  #pragma unroll
  for (int i = 0; i < 2; i++){
    int ch = i*256 + tid;
    int s = ch >> 3, pc = (ch & 7) * 8;
    const u16* src = xbc + (size_t)(b*2048 + t0 + s)*CONVD + h*64 + pc;
    u32x4 vx = *(const u32x4*)src;
    float dt = dt_soft[(size_t)(b*2048 + t0 + s)*64 + h];
    const u16* px = (const u16*)&vx;
    #pragma unroll
    for (int e = 0; e < 8; e++)
      sUt[(pc + e)*SUTS + s] = f2bf(bf2f(px[e]) * dt);
  }
  __syncthreads();

  // MFMA1: M[t][s] = sum_n C[t][n]*B[s][n]
  int tr = (wave & 1)*32, sc = (wave >> 1)*32;
  f32x4 aM[2][2];
  #pragma unroll
  for (int i=0;i<2;i++)
    #pragma unroll
    for (int j=0;j<2;j++) aM[i][j] = (f32x4){0.f,0.f,0.f,0.f};
  #pragma unroll
  for (int kk = 0; kk < 128; kk += 32){
    bf16x8 a0 = *(const bf16x8*)(sCM + (tr      + l15)*SBS + kk + quad*8);
    bf16x8 a1 = *(const bf16x8*)(sCM + (tr + 16 + l15)*SBS + kk + quad*8);
    bf16x8 b0 = *(const bf16x8*)(sB  + (sc      + l15)*SBS + kk + quad*8);
    bf16x8 b1 = *(const bf16x8*)(sB  + (sc + 16 + l15)*SBS + kk + quad*8);
    aM[0][0] = MFMA16(a0, b0, aM[0][0]);
    aM[0][1] = MFMA16(a0, b1, aM[0][1]);
    aM[1][0] = MFMA16(a1, b0, aM[1][0]);
    aM[1][1] = MFMA16(a1, b1, aM[1][1]);
  }
  __syncthreads();
  u16* sM = sCM;
  #pragma unroll
  for (int i = 0; i < 2; i++){
    #pragma unroll
    for (int j = 0; j < 2; j++){
      int scol = sc + j*16 + l15;
      #pragma unroll
      for (int r = 0; r < 4; r++){
        int trow = tr + i*16 + quad*4 + r;
        float v = 0.f;
        if (scol <= trow) v = aM[i][j][r] * __expf(sLa[trow] - sLa[scol]);
        sM[trow*SMS + scol] = f2bf(v);
      }
    }
  }
  __syncthreads();

  // MFMA2: Y[t][p] = sum_s M[t][s]*u[s][p]
  f32x4 aY[2][2];
  #pragma unroll
  for (int i=0;i<2;i++)
    #pragma unroll
    for (int j=0;j<2;j++) aY[i][j] = (f32x4){0.f,0.f,0.f,0.f};
  #pragma unroll
  for (int kk = 0; kk < 64; kk += 32){
    bf16x8 a0 = *(const bf16x8*)(sM  + (tr      + l15)*SMS  + kk + quad*8);
    bf16x8 a1 = *(const bf16x8*)(sM  + (tr + 16 + l15)*SMS  + kk + quad*8);
    bf16x8 b0 = *(const bf16x8*)(sUt + (sc      + l15)*SUTS + kk + quad*8);
    bf16x8 b1 = *(const bf16x8*)(sUt + (sc + 16 + l15)*SUTS + kk + quad*8);
    aY[0][0] = MFMA16(a0, b0, aY[0][0]);
    aY[0][1] = MFMA16(a0, b1, aY[0][1]);
    aY[1][0] = MFMA16(a1, b0, aY[1][0]);
    aY[1][1] = MFMA16(a1, b1, aY[1][1]);
  }
  #pragma unroll
  for (int i = 0; i < 2; i++){
    #pragma unroll
    for (int j = 0; j < 2; j++){
      int p = sc + j*16 + l15;
      #pragma unroll
      for (int r = 0; r < 4; r++){
        int t = tr + i*16 + quad*4 + r;
        y[(size_t)(b*2048 + t0 + t)*INTERD + h*64 + p] = f2bf(aY[i][j][r]);
      }
    }
  }

  // MFMA3: S[p][n] = sum_s u[s][p]*decay(s)*B[s][n]
  int pr = (wave & 1)*32, nw = (wave >> 1)*64;
  f32x4 aS[2][4];
  #pragma unroll
  for (int i=0;i<2;i++)
    #pragma unroll
    for (int j=0;j<4;j++) aS[i][j] = (f32x4){0.f,0.f,0.f,0.f};
  #pragma unroll
  for (int kk = 0; kk < 64; kk += 32){
    bf16x8 a0 = *(const bf16x8*)(sUt + (pr      + l15)*SUTS + kk + quad*8);
    bf16x8 a1 = *(const bf16x8*)(sUt + (pr + 16 + l15)*SUTS + kk + quad*8);
    #pragma unroll
    for (int j = 0; j < 4; j++){
      bf16x8 bb = *(const bf16x8*)(sBt + (nw + j*16 + l15)*64 + kk + quad*8);
      aS[0][j] = MFMA16(a0, bb, aS[0][j]);
      aS[1][j] = MFMA16(a1, bb, aS[1][j]);
    }
  }
  u16* Sl = S + ((size_t)bh*NCHUNK + q)*8192;
  #pragma unroll
  for (int i = 0; i < 2; i++){
    #pragma unroll
    for (int j = 0; j < 4; j++){
      int n = nw + j*16 + l15;
      #pragma unroll
      for (int r = 0; r < 4; r++){
        int p = pr + i*16 + quad*4 + r;
        Sl[p*NST + n] = f2bf(aS[i][j][r]);
      }
    }
  }
}

// ---------------------------------------------------------------------------
// Inter-chunk recurrence, in-place.
__global__ __launch_bounds__(256) void ssd_carry_kernel(
    u16* __restrict__ S, const float* __restrict__ cdexp)
{
  int idx = blockIdx.x * 256 + threadIdx.x;   // 2*64*8192
  int e = idx & 8191, bh = idx >> 13;
  float E = 0.f;
  for (int q = 0; q < NCHUNK; q++){
    size_t off = ((size_t)bh*NCHUNK + q)*8192 + e;
    float v = bf2f(S[off]);
    S[off] = f2bf(E);
    E = cdexp[bh*NCHUNK + q] * E + v;
  }
}

// ---------------------------------------------------------------------------
// Inter-chunk output: y += exp(la[t]) * C_t @ S_q^T + D*x
__global__ __launch_bounds__(256) void ssd_inter_kernel(
    const u16* __restrict__ xbc, const float* __restrict__ ldA,
    const u16* __restrict__ S, const u16* __restrict__ Dvec,
    u16* __restrict__ y)
{
  int q = blockIdx.x, h = blockIdx.y, b = blockIdx.z;
  int bh = b*64 + h;
  int t0 = q * QC;
  int tid = threadIdx.x, wave = tid >> 6, lane = tid & 63;
  int l15 = lane & 15, quad = lane >> 4;

  __shared__ u16 sC[64*SBS];
  __shared__ u16 sS[64*SBS];
  __shared__ float sLa[64];

  if (tid < 64){
    float v = ldA[(size_t)(b*2048 + t0 + tid)*64 + h];
    #pragma unroll
    for (int off = 1; off < 64; off <<= 1){
      float o = __shfl_up(v, off, 64);
      if (lane >= off) v += o;
    }
    sLa[tid] = v;
  }
  const u16* Sc = S + ((size_t)bh*NCHUNK + q)*8192;
  #pragma unroll
  for (int i = 0; i < 4; i++){
    int ch = i*256 + tid;
    int s = ch >> 4, nc = (ch & 15) * 8;
    *(u32x4*)(sC + s*SBS + nc) =
        *(const u32x4*)(xbc + (size_t)(b*2048 + t0 + s)*CONVD + 4224 + nc);
    *(u32x4*)(sS + s*SBS + nc) = *(const u32x4*)(Sc + s*NST + nc);
  }
  __syncthreads();

  int tr = (wave & 1)*32, pc = (wave >> 1)*32;
  f32x4 acc[2][2];
  #pragma unroll
  for (int i=0;i<2;i++)
    #pragma unroll
    for (int j=0;j<2;j++) acc[i][j] = (f32x4){0.f,0.f,0.f,0.f};
  #pragma unroll
  for (int kk = 0; kk < 128; kk += 32){
    bf16x8 a0 = *(const bf16x8*)(sC + (tr      + l15)*SBS + kk + quad*8);
    bf16x8 a1 = *(const bf16x8*)(sC + (tr + 16 + l15)*SBS + kk + quad*8);
    bf16x8 b0 = *(const bf16x8*)(sS + (pc      + l15)*SBS + kk + quad*8);
    bf16x8 b1 = *(const bf16x8*)(sS + (pc + 16 + l15)*SBS + kk + quad*8);
    acc[0][0] = MFMA16(a0, b0, acc[0][0]);
    acc[0][1] = MFMA16(a0, b1, acc[0][1]);
    acc[1][0] = MFMA16(a1, b0, acc[1][0]);
    acc[1][1] = MFMA16(a1, b1, acc[1][1]);
  }
  float Dh = bf2f(Dvec[h]);
  #pragma unroll
  for (int i = 0; i < 2; i++){
    #pragma unroll
    for (int j = 0; j < 2; j++){
      int p = pc + j*16 + l15;
      #pragma unroll
      for (int r = 0; r < 4; r++){
        int t = tr + i*16 + quad*4 + r;
        size_t row = (size_t)(b*2048 + t0 + t);
        size_t yo = row*INTERD + h*64 + p;
        float xv = bf2f(xbc[row*CONVD + h*64 + p]);
        float v = bf2f(y[yo]) + __expf(sLa[t]) * acc[i][j][r] + Dh * xv;
        y[yo] = f2bf(v);
      }
    }
  }
}

// ---------------------------------------------------------------------------
// RMSNorm * norm_w, gated by silu(0.25*z).
__global__ __launch_bounds__(256) void rmsnorm_gate_kernel(
    const u16* __restrict__ y, const u16* __restrict__ z,
    const u16* __restrict__ norm_w, u16* __restrict__ g)
{
  int rl = blockIdx.x;
  int tid = threadIdx.x, wave = tid >> 6, lane = tid & 63;
  const u16* yr = y + (size_t)rl*INTERD;
  float vy[16];
  float ss = 0.f;
  #pragma unroll
  for (int i = 0; i < 16; i++){
    int idx = i*256 + tid;
    float v = bf2f(yr[idx]);
    vy[i] = v;
    ss += v*v;
  }
  #pragma unroll
  for (int off = 32; off >= 1; off >>= 1) ss += __shfl_xor(ss, off, 64);
  __shared__ float red[4];
  if (lane == 0) red[wave] = ss;
  __syncthreads();
  float tot = red[0] + red[1] + red[2] + red[3];
  float rstd = rsqrtf(tot * (1.f/4096.f) + 1e-5f);
  const u16* zr = z + (size_t)rl*INTERD;
  u16* gr = g + (size_t)rl*INTERD;
  #pragma unroll
  for (int i = 0; i < 16; i++){
    int idx = i*256 + tid;
    float v = vy[i] * rstd * bf2f(norm_w[idx]);
    float zv = 0.25f * bf2f(zr[idx]);
    float sig = 1.f / (1.f + __expf(-zv));
    gr[idx] = f2bf(v * zv * sig);
  }
}

// ---------------------------------------------------------------------------
extern "C" void kernel_launch(void* const* d_in, const int* in_sizes, int n_in,
                              void* d_out, int out_size, void* d_ws, size_t ws_size,
                              hipStream_t stream)
{
  const void* hidden_r    = d_in[0];
  const void* in_proj_r   = d_in[1];
  const void* conv_w_r    = d_in[2];
  const void* conv_b_r    = d_in[3];
  const void* A_log_r     = d_in[4];
  const void* Dvec_r      = d_in[5];
  const void* dt_bias_r   = d_in[6];
  const void* norm_w_r    = d_in[7];
  const void* out_proj_r  = d_in[8];
  float* out = (float*)d_out;          // reference output dtype = float32
  char* ws = (char*)d_ws;

  // workspace layout (bytes); peak = 174,735,360 (proven in-bounds in r3)
  u16*   z     = (u16*)(ws + 0);               // 33,554,432
  u16*   xbcr  = (u16*)(ws + 33554432ull);     // 35,651,584 (dead after conv)
  u16*   yb    = (u16*)(ws + 33554432ull);     // 33,554,432 overlays xbcr
  u16*   dtraw = (u16*)(ws + 69206016ull);     //    524,288
  u16*   xbc   = (u16*)(ws + 69730304ull);     // 35,651,584 (dead after inter)
  u16*   w2b   = (u16*)(ws + 69730304ull);     // 16,777,216 overlays xbc (late)  [2048][4096] = out_proj^T
  float* dt_s  = (float*)(ws + 105381888ull);  //  1,048,576
  float* lda   = (float*)(ws + 106430464ull);  //  1,048,576
  float* cdexp = (float*)(ws + 107479040ull);  //     16,384
  u32*   flag  = (u32*)(ws + 107495424ull);    //        256
  u16*   svec  = (u16*)(ws + 107495680ull);    //     52,096 packed small vectors
  u16*   cw_b  = svec;                         // conv_w  17408
  u16*   cb_b  = svec + 17408;                 // conv_b   4352
  u16*   al_b  = svec + 21760;                 // A_log      64
  u16*   d_b   = svec + 21824;                 // D          64
  u16*   db_b  = svec + 21888;                 // dt_bias    64
  u16*   nw_b  = svec + 21952;                 // norm_w   4096
  u16*   S     = (u16*)(ws + 107626496ull);    // 67,108,864 -> end 174,735,360
  u16*   hb    = (u16*)(ws + 107626496ull);    // 16,777,216 overlays S (early)
  u16*   w1b   = (u16*)(ws + 124403712ull);    // 35,127,296 overlays S (early) [8576][2048] = in_proj^T padded -> end 159,531,008
  u16*   g     = (u16*)(ws + 107626496ull);    // 33,554,432 overlays S (late)

  // 0) dtype detect + canonicalize to bf16 (weights transposed for m97 GEMM)
  detect_kernel<<<1, 256, 0, stream>>>(hidden_r, flag);
  cvt_kernel<<<4096, 256, 0, stream>>>(hidden_r, hb, 8388608, flag);
  cvt_transpose_kernel<<<dim3(134, 32), 256, 0, stream>>>(
      in_proj_r, w1b, 2048, 8512, 8576, flag);
  cvt_small_kernel<<<102, 256, 0, stream>>>(conv_w_r, conv_b_r, A_log_r,
      Dvec_r, dt_bias_r, norm_w_r, svec, flag);
  // 1) GEMM1: split epilogue -> z / xbcr / dtraw  (M=4096, Npad=8576, K=2048)
  gemm_kernel<<<dim3(67, 32), 256, 0, stream>>>(
      hb, w1b, z, xbcr, dtraw, (float*)nullptr, 4096, 8576, 2048, 1);
  // 2) conv + silu (0.5 mup folded)
  conv_silu_kernel<<<dim3(17, 4096), 256, 0, stream>>>(xbcr, cw_b, cb_b, xbc);
  // 3) dt softplus + log-decays
  dt_kernel<<<1024, 256, 0, stream>>>(dtraw, db_b, al_b, dt_s, lda);
  chunk_decay_kernel<<<16, 256, 0, stream>>>(lda, cdexp);
  // 4) SSD chunked scan (validated against exact scan in r4)
  ssd_intra_kernel<<<dim3(NCHUNK, 64, 2), 256, 0, stream>>>(xbc, dt_s, lda, S, yb);
  ssd_carry_kernel<<<4096, 256, 0, stream>>>(S, cdexp);
  ssd_inter_kernel<<<dim3(NCHUNK, 64, 2), 256, 0, stream>>>(xbc, lda, S, d_b, yb);
  // 5) late transpose-conversion of out_proj into xbc's slot (xbc dead after inter)
  cvt_transpose_kernel<<<dim3(32, 64), 256, 0, stream>>>(
      out_proj_r, w2b, 4096, 2048, 2048, flag);
  // 6) RMSNorm + silu(0.25*z) gate (g overlays S)
  rmsnorm_gate_kernel<<<4096, 256, 0, stream>>>(yb, z, nw_b, g);
  // 7) GEMM2: out = g @ out_proj  (M=4096, N=2048, K=4096) -> fp32 out
  gemm_kernel<<<dim3(16, 32), 256, 0, stream>>>(
      g, w2b, (u16*)nullptr, (u16*)nullptr, (u16*)nullptr, out,
      4096, 2048, 4096, 2);
}

// Round 3
// 718.752 us; speedup vs baseline: 1.9293x; 1.0020x over previous
//
#include <hip/hip_runtime.h>
#include <stdint.h>

typedef unsigned short u16;
typedef unsigned int   u32;
typedef __attribute__((ext_vector_type(8))) short bf16x8;
typedef __attribute__((ext_vector_type(4))) float f32x4;
typedef __attribute__((ext_vector_type(4))) u32   u32x4;

static __device__ __forceinline__ float bf2f(u16 v){
  u32 u = ((u32)v) << 16;
  return __builtin_bit_cast(float, u);
}
static __device__ __forceinline__ u16 f2bf(float f){
  u32 u = __builtin_bit_cast(u32, f);
  return (u16)((u + 0x7fffu + ((u >> 16) & 1u)) >> 16);
}

#define MFMA16(a,b,c) __builtin_amdgcn_mfma_f32_16x16x32_bf16((a),(b),(c),0,0,0)

// async global->LDS, 16B per lane (emits global_load_lds_dwordx4)
typedef const __attribute__((address_space(1))) char glb_c;
typedef __attribute__((address_space(3))) char lds_c;
static __device__ __forceinline__ void gload_lds16(const void* g, void* l){
  __builtin_amdgcn_global_load_lds((glb_c*)g, (lds_c*)l, 16, 0, 0);
}

// Model dims
#define SEQN   2048
#define PROJD  8512
#define CONVD  4352
#define INTERD 4096
#define NST    128
#define QC     64
#define NCHUNK 32

// ---------------------------------------------------------------------------
// Input dtype detection (fp32 confirmed; kept for robustness).
__global__ __launch_bounds__(256) void detect_kernel(
    const void* __restrict__ hidden, u32* __restrict__ flag)
{
  __shared__ int cnt;
  if (threadIdx.x == 0) cnt = 0;
  __syncthreads();
  if (threadIdx.x < 128){
    u16 v = ((const u16*)hidden)[threadIdx.x * 2];
    int e = (v >> 7) & 0xFF;
    int plaus = (v == 0) || (e >= 0x70 && e <= 0x8F);
    atomicAdd(&cnt, plaus);
  }
  __syncthreads();
  if (threadIdx.x == 0) *flag = (cnt < 64) ? 1u : 0u;   // 1 = fp32 inputs
}

__global__ __launch_bounds__(256) void cvt_kernel(
    const void* __restrict__ src, u16* __restrict__ dst, int n,
    const u32* __restrict__ flag)
{
  bool isf32 = (*flag != 0);
  int stride = gridDim.x * 256;
  for (int i = blockIdx.x*256 + threadIdx.x; i < n; i += stride){
    if (isf32) dst[i] = f2bf(((const float*)src)[i]);
    else       dst[i] = ((const u16*)src)[i];
  }
}

// Convert + transpose weights: src [K][N] (fp32 or bf16) -> dst [Npad][K] bf16.
// Rows n >= N are zero-filled (pad for tile-exact GEMM).
__global__ __launch_bounds__(256) void cvt_transpose_kernel(
    const void* __restrict__ src, u16* __restrict__ dst,
    int K, int N, int Npad, const u32* __restrict__ flag)
{
  bool isf32 = (*flag != 0);
  __shared__ u16 tile[64][72];
  int n0 = blockIdx.x * 64, k0 = blockIdx.y * 64;
  int tid = threadIdx.x;
  int tr = tid >> 6;     // wave id 0..3
  int tc = tid & 63;
  #pragma unroll
  for (int i = 0; i < 16; i++){
    int k = i*4 + tr;
    int gk = k0 + k, gn = n0 + tc;
    float v = 0.f;
    if (gk < K && gn < N)
      v = isf32 ? ((const float*)src)[(size_t)gk*N + gn]
                : bf2f(((const u16*)src)[(size_t)gk*N + gn]);
    tile[k][tc] = f2bf(v);
  }
  __syncthreads();
  #pragma unroll
  for (int i = 0; i < 16; i++){
    int n = i*4 + tr;
    int gn = n0 + n;
    if (gn < Npad && (k0 + tc) < K)
      dst[(size_t)gn*K + k0 + tc] = tile[tc][n];
  }
}

__global__ __launch_bounds__(256) void cvt_small_kernel(
    const void* cw, const void* cb, const void* al, const void* dv,
    const void* db, const void* nw, u16* __restrict__ base,
    const u32* __restrict__ flag)
{
  bool isf32 = (*flag != 0);
  int idx = blockIdx.x*256 + threadIdx.x;   // 0 .. 26047
  if (idx >= 26048) return;
  const void* src; int off;
  if      (idx < 17408){ src = cw; off = idx;          }
  else if (idx < 21760){ src = cb; off = idx - 17408;  }
  else if (idx < 21824){ src = al; off = idx - 21760;  }
  else if (idx < 21888){ src = dv; off = idx - 21824;  }
  else if (idx < 21952){ src = db; off = idx - 21888;  }
  else                 { src = nw; off = idx - 21952;  }
  u16 v = isf32 ? f2bf(((const float*)src)[off]) : ((const u16*)src)[off];
  base[idx] = v;
}

// ---------------------------------------------------------------------------
// C = A[M,K] @ Bt[N,K]^T (row-major bf16, B pre-transposed), fp32 MFMA accum.
// 256x256 tile, BK=64, 512 threads (8 waves, 2Mx4N), 128 KiB LDS dbuf,
// m201-faithful 8-phase schedule: per phase {ds_read THIS phase's frags |
// stage 1 half-tile | (vmcnt gate) | barrier | lgkmcnt(0) | 16 MFMA | barrier}.
// Counted vmcnt ledger (steady state; 1 STG = 2 loads):
//   enter iter: 4 in flight (B of odd tile T1)
//   p0 +A1h0=6  p1 +A1h1=8  p2 +B2h0=10  p3 +B2h1=12, vmcnt(4) -> T1 landed
//   p4 +A2h0=6  p5 +A2h1=8  p6 +B3h0=10  p7 +B3h1=12, vmcnt(4) -> T2 landed
// Last iter: p3 vmcnt(0), no stages/gates after.
// WAR: each stage targets a region whose last ds_read completed at least one
// barrier earlier (reads complete at their phase's lgkmcnt(0)).
// Requires: M%256==0, N%256==0 (pad), K%128==0, nwg%8==0.
__global__ __launch_bounds__(512, 2) void gemm_kernel(
    const u16* __restrict__ A, const u16* __restrict__ Bt,
    u16* __restrict__ C0, u16* __restrict__ C1, u16* __restrict__ C2,
    float* __restrict__ CF,
    int M, int N, int K, int mode)
{
  __shared__ u16 smem[65536];   // 128 KiB: [buf0: A(32KB)|B(32KB)][buf1: ...]

  const int nbx = gridDim.x;
  const int nwg = nbx * gridDim.y;
  const int bid = blockIdx.y * nbx + blockIdx.x;
  const int swz = (bid & 7) * (nwg >> 3) + (bid >> 3);
  const int m0 = (swz / nbx) * 256, n0 = (swz % nbx) * 256;

  const int tid = threadIdx.x;
  const int wave = tid >> 6, lane = tid & 63;
  const int l15 = lane & 15, quad = lane >> 4;
  const int wm = wave >> 2, wn = wave & 3;   // 2 x 4 wave grid

  // staging: thread covers row (tid>>3) of each 64-row group, chunk (tid&7);
  // global source chunk XOR-swizzled, LDS write linear (both-sides rule).
  const size_t Kb = (size_t)K * 2;
  const int srow = tid >> 3;
  const int schk = (tid & 7) ^ (srow & 7);
  const char* Abp = (const char*)A  + (size_t)(m0 + srow) * Kb + schk * 16;
  const char* Bbp = (const char*)Bt + (size_t)(n0 + srow) * Kb + schk * 16;
  char* ldsb = (char*)smem + wave * 1024;   // wave-uniform; HW adds lane*16

  // ds_read bases per [buffer][kk2]; fragment row offset folds to immediate.
  const int aoff0 = ((quad    ) ^ (l15 & 7)) << 4;
  const int aoff1 = ((quad + 4) ^ (l15 & 7)) << 4;
  const char* ardb[2][2];
  const char* brdb[2][2];
  #pragma unroll
  for (int c = 0; c < 2; c++){
    ardb[c][0] = (const char*)smem + c*65536 + (wm*128 + l15)*128 + aoff0;
    ardb[c][1] = (const char*)smem + c*65536 + (wm*128 + l15)*128 + aoff1;
    brdb[c][0] = (const char*)smem + c*65536 + 32768 + (wn*64 + l15)*128 + aoff0;
    brdb[c][1] = (const char*)smem + c*65536 + 32768 + (wn*64 + l15)*128 + aoff1;
  }

  f32x4 acc[8][4];
  #pragma unroll
  for (int i = 0; i < 8; i++)
    #pragma unroll
    for (int j = 0; j < 4; j++) acc[i][j] = (f32x4){0.f,0.f,0.f,0.f};

  bf16x8 af[4];    // A frags for current phase quadrant: [mf2*2+kk2]
  bf16x8 bfr[8];   // B frags for current tile: [nf*2+kk2]

#define STG(ptr, par, isB, h, kt) do{                                    \
    const char* _s = (ptr) + (size_t)((h)*128)*Kb + (size_t)(kt)*128;    \
    char* _d = ldsb + (par)*65536 + ((isB)?32768:0) + (h)*16384;         \
    gload_lds16(_s, _d);                                                 \
    gload_lds16(_s + 64*Kb, _d + 8192);                                  \
  }while(0)

  // ---- prologue: stage T0 fully + B(T1); keep B(T1) in flight
  STG(Bbp,0,1,0,0); STG(Bbp,0,1,1,0);
  STG(Abp,0,0,0,0); STG(Abp,0,0,1,0);
  STG(Bbp,1,1,0,1); STG(Bbp,1,1,1,1);
  asm volatile("s_waitcnt vmcnt(4)" ::: "memory");
  __builtin_amdgcn_s_barrier();

  const int NT = K >> 6;
  for (int I = 0; I < (NT >> 1); ++I){
    const int T1 = 2*I+1, T2 = 2*I+2, T3 = 2*I+3;
    const bool pf = (T2 < NT);
    #pragma unroll
    for (int p = 0; p < 8; ++p){
      const int q = p & 3, c = p >> 2;   // quadrant, buffer/tile parity
      // 1) ds_read THIS phase's fragments (A quadrant q; B of tile if q==0)
      #pragma unroll
      for (int k = 0; k < 2; k++){
        af[0+k] = *(const bf16x8*)(ardb[c][k] + (2*q+0)*2048);
        af[2+k] = *(const bf16x8*)(ardb[c][k] + (2*q+1)*2048);
      }
      if (q == 0){
        #pragma unroll
        for (int nf = 0; nf < 4; nf++)
          #pragma unroll
          for (int k = 0; k < 2; k++)
            bfr[nf*2+k] = *(const bf16x8*)(brdb[c][k] + nf*2048);
      }
      // 2) stage one half-tile; 3) counted vmcnt gates at p3/p7
      if      (p == 0) STG(Abp,1,0,0,T1);
      else if (p == 1) STG(Abp,1,0,1,T1);
      else if (p == 2){ if (pf) STG(Bbp,0,1,0,T2); }
      else if (p == 3){
        if (pf){ STG(Bbp,0,1,1,T2);
                 asm volatile("s_waitcnt vmcnt(4)" ::: "memory"); }
        else     asm volatile("s_waitcnt vmcnt(0)" ::: "memory");
      }
      else if (p == 4){ if (pf) STG(Abp,0,0,0,T2); }
      else if (p == 5){ if (pf) STG(Abp,0,0,1,T2); }
      else if (p == 6){ if (pf) STG(Bbp,1,1,0,T3); }
      else            { if (pf){ STG(Bbp,1,1,1,T3);
                 asm volatile("s_waitcnt vmcnt(4)" ::: "memory"); } }
      asm volatile("" ::: "memory");
      __builtin_amdgcn_s_barrier();
      asm volatile("s_waitcnt lgkmcnt(0)" ::: "memory");
      // 4) MFMA: quadrant q of tile in buffer c
      __builtin_amdgcn_s_setprio(1);
      #pragma unroll
      for (int mf2 = 0; mf2 < 2; ++mf2)
        #pragma unroll
        for (int nf = 0; nf < 4; ++nf)
          #pragma unroll
          for (int k = 0; k < 2; k++)
            acc[2*q+mf2][nf] =
                MFMA16(af[mf2*2+k], bfr[nf*2+k], acc[2*q+mf2][nf]);
      __builtin_amdgcn_s_setprio(0);
      asm volatile("" ::: "memory");
      __builtin_amdgcn_s_barrier();
    }
  }
#undef STG

  // ---- epilogue
  #pragma unroll
  for (int nf = 0; nf < 4; nf++){
    int col = n0 + wn*64 + nf*16 + l15;
    #pragma unroll
    for (int mf = 0; mf < 8; mf++){
      #pragma unroll
      for (int r = 0; r < 4; r++){
        int row = m0 + wm*128 + mf*16 + quad*4 + r;
        float fv = acc[mf][nf][r];
        if (mode == 2){
          if (col < N) CF[(size_t)row*N + col] = fv;
        } else if (mode == 0){
          if (col < N) C0[(size_t)row*N + col] = f2bf(fv);
        } else {
          u16 v = f2bf(fv);
          if      (col < 4096) C0[(size_t)row*4096 + col] = v;
          else if (col < 8448) C1[(size_t)row*CONVD + (col - 4096)] = v;
          else if (col < 8512) C2[(size_t)row*64 + (col - 8448)] = v;
          // cols 8512..8703 are zero-padding, dropped
        }
      }
    }
  }
}

// ---------------------------------------------------------------------------
// Causal depthwise conv (K=4, left pad 3) + bias + silu; 0.5 mup folded.
__global__ __launch_bounds__(256) void conv_silu_kernel(
    const u16* __restrict__ xbcr, const u16* __restrict__ conv_w,
    const u16* __restrict__ conv_b, u16* __restrict__ xbc)
{
  int c  = blockIdx.x * 256 + threadIdx.x;   // 17*256 = 4352 exact
  int rl = blockIdx.y;
  int b = rl >> 11, l = rl & 2047;
  float w[4];
  #pragma unroll
  for (int k=0;k<4;k++) w[k] = 0.5f * bf2f(conv_w[c*4 + k]);
  float acc = bf2f(conv_b[c]);
  #pragma unroll
  for (int k=0;k<4;k++){
    int s = l + k - 3;
    if (s >= 0) acc += bf2f(xbcr[(size_t)(b*2048 + s)*CONVD + c]) * w[k];
  }
  float sig = 1.f / (1.f + __expf(-acc));
  xbc[(size_t)rl*CONVD + c] = f2bf(acc * sig);
}

// ---------------------------------------------------------------------------
// dt_soft = softplus(dtraw + dt_bias); ldA = dt_soft * (-exp(A_log)).
__global__ __launch_bounds__(256) void dt_kernel(
    const u16* __restrict__ dtraw, const u16* __restrict__ dt_bias,
    const u16* __restrict__ A_log, float* __restrict__ dt_soft,
    float* __restrict__ ldA)
{
  int idx = blockIdx.x * 256 + threadIdx.x;  // 4096*64
  int h = idx & 63;
  float x = bf2f(dtraw[idx]) + bf2f(dt_bias[h]);
  float sp = (x > 20.f) ? x : log1pf(expf(x));
  float A = -expf(bf2f(A_log[h]));
  dt_soft[idx] = sp;
  ldA[idx] = sp * A;
}

__global__ __launch_bounds__(256) void chunk_decay_kernel(
    const float* __restrict__ ldA, float* __restrict__ cdexp)
{
  int idx = blockIdx.x * 256 + threadIdx.x;  // 4096
  int q = idx & 31, bh = idx >> 5;
  int b = bh >> 6, h = bh & 63;
  float s = 0.f;
  int t0 = q * QC;
  for (int t = 0; t < QC; t++) s += ldA[(size_t)(b*2048 + t0 + t)*64 + h];
  cdexp[idx] = expf(s);
}

// ---------------------------------------------------------------------------
// SSD intra-chunk (validated in r4 bisection: matches exact scan).
#define SBS  136
#define SUTS 80
#define SMS  80
__global__ __launch_bounds__(256) void ssd_intra_kernel(
    const u16* __restrict__ xbc, const float* __restrict__ dt_soft,
    const float* __restrict__ ldA, u16* __restrict__ S,
    u16* __restrict__ y)
{
  int q = blockIdx.x, h = blockIdx.y, b = blockIdx.z;
  int bh = b*64 + h;
  int t0 = q * QC;
  int tid = threadIdx.x, wave = tid >> 6, lane = tid & 63;
  int l15 = lane & 15, quad = lane >> 4;

  __shared__ u16 sB [64*SBS];
  __shared__ u16 sCM[64*SBS];
  __shared__ u16 sBt[128*64];
  __shared__ u16 sUt[64*SUTS];
  __shared__ float sLa[64];
  __shared__ float sW[64];

  if (tid < 64){
    float v = ldA[(size_t)(b*2048 + t0 + tid)*64 + h];
    #pragma unroll
    for (int off = 1; off < 64; off <<= 1){
      float o = __shfl_up(v, off, 64);
      if (lane >= off) v += o;
    }
    sLa[tid] = v;
  }
  __syncthreads();
  float laE = sLa[63];
  if (tid < 64) sW[tid] = __expf(laE - sLa[tid]);
  __syncthreads();

  #pragma unroll
  for (int i = 0; i < 4; i++){
    int ch = i*256 + tid;
    int s = ch >> 4, nc = (ch & 15) * 8;
    const u16* src = xbc + (size_t)(b*2048 + t0 + s)*CONVD;
    u32x4 vb = *(const u32x4*)(src + 4096 + nc);
    u32x4 vc = *(const u32x4*)(src + 4224 + nc);
    *(u32x4*)(sB  + s*SBS + nc) = vb;
    *(u32x4*)(sCM + s*SBS + nc) = vc;
    float wdec = sW[s];
    const u16* pb = (const u16*)&vb;
    #pragma unroll
    for (int e = 0; e < 8; e++)
      sBt[(nc + e)*64 + s] = f2bf(bf2f(pb[e]) * wdec);
  }
  #pragma unroll
  for (int i = 0; i < 2; i++){
    int ch = i*256 + tid;
    int s = ch >> 3, pc = (ch & 7) * 8;
    const u16* src = xbc + (size_t)(b*2048 + t0 + s)*CONVD + h*64 + pc;
    u32x4 vx = *(const u32x4*)src;
    float dt = dt_soft[(size_t)(b*2048 + t0 + s)*64 + h];
    const u16* px = (const u16*)&vx;
    #pragma unroll
    for (int e = 0; e < 8; e++)
      sUt[(pc + e)*SUTS + s] = f2bf(bf2f(px[e]) * dt);
  }
  __syncthreads();

  // MFMA1: M[t][s] = sum_n C[t][n]*B[s][n]
  int tr = (wave & 1)*32, sc = (wave >> 1)*32;
  f32x4 aM[2][2];
  #pragma unroll
  for (int i=0;i<2;i++)
    #pragma unroll
    for (int j=0;j<2;j++) aM[i][j] = (f32x4){0.f,0.f,0.f,0.f};
  #pragma unroll
  for (int kk = 0; kk < 128; kk += 32){
    bf16x8 a0 = *(const bf16x8*)(sCM + (tr      + l15)*SBS + kk + quad*8);
    bf16x8 a1 = *(const bf16x8*)(sCM + (tr + 16 + l15)*SBS + kk + quad*8);
    bf16x8 b0 = *(const bf16x8*)(sB  + (sc      + l15)*SBS + kk + quad*8);
    bf16x8 b1 = *(const bf16x8*)(sB  + (sc + 16 + l15)*SBS + kk + quad*8);
    aM[0][0] = MFMA16(a0, b0, aM[0][0]);
    aM[0][1] = MFMA16(a0, b1, aM[0][1]);
    aM[1][0] = MFMA16(a1, b0, aM[1][0]);
    aM[1][1] = MFMA16(a1, b1, aM[1][1]);
  }
  __syncthreads();
  u16* sM = sCM;
  #pragma unroll
  for (int i = 0; i < 2; i++){
    #pragma unroll
    for (int j = 0; j < 2; j++){
      int scol = sc + j*16 + l15;
      #pragma unroll
      for (int r = 0; r < 4; r++){
        int trow = tr + i*16 + quad*4 + r;
        float v = 0.f;
        if (scol <= trow) v = aM[i][j][r] * __expf(sLa[trow] - sLa[scol]);
        sM[trow*SMS + scol] = f2bf(v);
      }
    }
  }
  __syncthreads();

  // MFMA2: Y[t][p] = sum_s M[t][s]*u[s][p]
  f32x4 aY[2][2];
  #pragma unroll
  for (int i=0;i<2;i++)
    #pragma unroll
    for (int j=0;j<2;j++) aY[i][j] = (f32x4){0.f,0.f,0.f,0.f};
  #pragma unroll
  for (int kk = 0; kk < 64; kk += 32){
    bf16x8 a0 = *(const bf16x8*)(sM  + (tr      + l15)*SMS  + kk + quad*8);
    bf16x8 a1 = *(const bf16x8*)(sM  + (tr + 16 + l15)*SMS  + kk + quad*8);
    bf16x8 b0 = *(const bf16x8*)(sUt + (sc      + l15)*SUTS + kk + quad*8);
    bf16x8 b1 = *(const bf16x8*)(sUt + (sc + 16 + l15)*SUTS + kk + quad*8);
    aY[0][0] = MFMA16(a0, b0, aY[0][0]);
    aY[0][1] = MFMA16(a0, b1, aY[0][1]);
    aY[1][0] = MFMA16(a1, b0, aY[1][0]);
    aY[1][1] = MFMA16(a1, b1, aY[1][1]);
  }
  #pragma unroll
  for (int i = 0; i < 2; i++){
    #pragma unroll
    for (int j = 0; j < 2; j++){
      int p = sc + j*16 + l15;
      #pragma unroll
      for (int r = 0; r < 4; r++){
        int t = tr + i*16 + quad*4 + r;
        y[(size_t)(b*2048 + t0 + t)*INTERD + h*64 + p] = f2bf(aY[i][j][r]);
      }
    }
  }

  // MFMA3: S[p][n] = sum_s u[s][p]*decay(s)*B[s][n]
  int pr = (wave & 1)*32, nw = (wave >> 1)*64;
  f32x4 aS[2][4];
  #pragma unroll
  for (int i=0;i<2;i++)
    #pragma unroll
    for (int j=0;j<4;j++) aS[i][j] = (f32x4){0.f,0.f,0.f,0.f};
  #pragma unroll
  for (int kk = 0; kk < 64; kk += 32){
    bf16x8 a0 = *(const bf16x8*)(sUt + (pr      + l15)*SUTS + kk + quad*8);
    bf16x8 a1 = *(const bf16x8*)(sUt + (pr + 16 + l15)*SUTS + kk + quad*8);
    #pragma unroll
    for (int j = 0; j < 4; j++){
      bf16x8 bb = *(const bf16x8*)(sBt + (nw + j*16 + l15)*64 + kk + quad*8);
      aS[0][j] = MFMA16(a0, bb, aS[0][j]);
      aS[1][j] = MFMA16(a1, bb, aS[1][j]);
    }
  }
  u16* Sl = S + ((size_t)bh*NCHUNK + q)*8192;
  #pragma unroll
  for (int i = 0; i < 2; i++){
    #pragma unroll
    for (int j = 0; j < 4; j++){
      int n = nw + j*16 + l15;
      #pragma unroll
      for (int r = 0; r < 4; r++){
        int p = pr + i*16 + quad*4 + r;
        Sl[p*NST + n] = f2bf(aS[i][j][r]);
      }
    }
  }
}

// ---------------------------------------------------------------------------
// Inter-chunk recurrence, in-place.
__global__ __launch_bounds__(256) void ssd_carry_kernel(
    u16* __restrict__ S, const float* __restrict__ cdexp)
{
  int idx = blockIdx.x * 256 + threadIdx.x;   // 2*64*8192
  int e = idx & 8191, bh = idx >> 13;
  float E = 0.f;
  for (int q = 0; q < NCHUNK; q++){
    size_t off = ((size_t)bh*NCHUNK + q)*8192 + e;
    float v = bf2f(S[off]);
    S[off] = f2bf(E);
    E = cdexp[bh*NCHUNK + q] * E + v;
  }
}

// ---------------------------------------------------------------------------
// Inter-chunk output: y += exp(la[t]) * C_t @ S_q^T + D*x
__global__ __launch_bounds__(256) void ssd_inter_kernel(
    const u16* __restrict__ xbc, const float* __restrict__ ldA,
    const u16* __restrict__ S, const u16* __restrict__ Dvec,
    u16* __restrict__ y)
{
  int q = blockIdx.x, h = blockIdx.y, b = blockIdx.z;
  int bh = b*64 + h;
  int t0 = q * QC;
  int tid = threadIdx.x, wave = tid >> 6, lane = tid & 63;
  int l15 = lane & 15, quad = lane >> 4;

  __shared__ u16 sC[64*SBS];
  __shared__ u16 sS[64*SBS];
  __shared__ float sLa[64];

  if (tid < 64){
    float v = ldA[(size_t)(b*2048 + t0 + tid)*64 + h];
    #pragma unroll
    for (int off = 1; off < 64; off <<= 1){
      float o = __shfl_up(v, off, 64);
      if (lane >= off) v += o;
    }
    sLa[tid] = v;
  }
  const u16* Sc = S + ((size_t)bh*NCHUNK + q)*8192;
  #pragma unroll
  for (int i = 0; i < 4; i++){
    int ch = i*256 + tid;
    int s = ch >> 4, nc = (ch & 15) * 8;
    *(u32x4*)(sC + s*SBS + nc) =
        *(const u32x4*)(xbc + (size_t)(b*2048 + t0 + s)*CONVD + 4224 + nc);
    *(u32x4*)(sS + s*SBS + nc) = *(const u32x4*)(Sc + s*NST + nc);
  }
  __syncthreads();

  int tr = (wave & 1)*32, pc = (wave >> 1)*32;
  f32x4 acc[2][2];
  #pragma unroll
  for (int i=0;i<2;i++)
    #pragma unroll
    for (int j=0;j<2;j++) acc[i][j] = (f32x4){0.f,0.f,0.f,0.f};
  #pragma unroll
  for (int kk = 0; kk < 128; kk += 32){
    bf16x8 a0 = *(const bf16x8*)(sC + (tr      + l15)*SBS + kk + quad*8);
    bf16x8 a1 = *(const bf16x8*)(sC + (tr + 16 + l15)*SBS + kk + quad*8);
    bf16x8 b0 = *(const bf16x8*)(sS + (pc      + l15)*SBS + kk + quad*8);
    bf16x8 b1 = *(const bf16x8*)(sS + (pc + 16 + l15)*SBS + kk + quad*8);
    acc[0][0] = MFMA16(a0, b0, acc[0][0]);
    acc[0][1] = MFMA16(a0, b1, acc[0][1]);
    acc[1][0] = MFMA16(a1, b0, acc[1][0]);
    acc[1][1] = MFMA16(a1, b1, acc[1][1]);
  }
  float Dh = bf2f(Dvec[h]);
  #pragma unroll
  for (int i = 0; i < 2; i++){
    #pragma unroll
    for (int j = 0; j < 2; j++){
      int p = pc + j*16 + l15;
      #pragma unroll
      for (int r = 0; r < 4; r++){
        int t = tr + i*16 + quad*4 + r;
        size_t row = (size_t)(b*2048 + t0 + t);
        size_t yo = row*INTERD + h*64 + p;
        float xv = bf2f(xbc[row*CONVD + h*64 + p]);
        float v = bf2f(y[yo]) + __expf(sLa[t]) * acc[i][j][r] + Dh * xv;
        y[yo] = f2bf(v);
      }
    }
  }
}

// ---------------------------------------------------------------------------
// RMSNorm * norm_w, gated by silu(0.25*z).
__global__ __launch_bounds__(256) void rmsnorm_gate_kernel(
    const u16* __restrict__ y, const u16* __restrict__ z,
    const u16* __restrict__ norm_w, u16* __restrict__ g)
{
  int rl = blockIdx.x;
  int tid = threadIdx.x, wave = tid >> 6, lane = tid & 63;
  const u16* yr = y + (size_t)rl*INTERD;
  float vy[16];
  float ss = 0.f;
  #pragma unroll
  for (int i = 0; i < 16; i++){
    int idx = i*256 + tid;
    float v = bf2f(yr[idx]);
    vy[i] = v;
    ss += v*v;
  }
  #pragma unroll
  for (int off = 32; off >= 1; off >>= 1) ss += __shfl_xor(ss, off, 64);
  __shared__ float red[4];
  if (lane == 0) red[wave] = ss;
  __syncthreads();
  float tot = red[0] + red[1] + red[2] + red[3];
  float rstd = rsqrtf(tot * (1.f/4096.f) + 1e-5f);
  const u16* zr = z + (size_t)rl*INTERD;
  u16* gr = g + (size_t)rl*INTERD;
  #pragma unroll
  for (int i = 0; i < 16; i++){
    int idx = i*256 + tid;
    float v = vy[i] * rstd * bf2f(norm_w[idx]);
    float zv = 0.25f * bf2f(zr[idx]);
    float sig = 1.f / (1.f + __expf(-zv));
    gr[idx] = f2bf(v * zv * sig);
  }
}

// ---------------------------------------------------------------------------
extern "C" void kernel_launch(void* const* d_in, const int* in_sizes, int n_in,
                              void* d_out, int out_size, void* d_ws, size_t ws_size,
                              hipStream_t stream)
{
  const void* hidden_r    = d_in[0];
  const void* in_proj_r   = d_in[1];
  const void* conv_w_r    = d_in[2];
  const void* conv_b_r    = d_in[3];
  const void* A_log_r     = d_in[4];
  const void* Dvec_r      = d_in[5];
  const void* dt_bias_r   = d_in[6];
  const void* norm_w_r    = d_in[7];
  const void* out_proj_r  = d_in[8];
  float* out = (float*)d_out;          // reference output dtype = float32
  char* ws = (char*)d_ws;

  // workspace layout (bytes); peak = 174,735,360 (proven in-bounds in r3)
  u16*   z     = (u16*)(ws + 0);               // 33,554,432
  u16*   xbcr  = (u16*)(ws + 33554432ull);     // 35,651,584 (dead after conv)
  u16*   yb    = (u16*)(ws + 33554432ull);     // 33,554,432 overlays xbcr
  u16*   dtraw = (u16*)(ws + 69206016ull);     //    524,288
  u16*   xbc   = (u16*)(ws + 69730304ull);     // 35,651,584 (dead after inter)
  u16*   w2b   = (u16*)(ws + 69730304ull);     // 16,777,216 overlays xbc (late)  [2048][4096] = out_proj^T
  float* dt_s  = (float*)(ws + 105381888ull);  //  1,048,576
  float* lda   = (float*)(ws + 106430464ull);  //  1,048,576
  float* cdexp = (float*)(ws + 107479040ull);  //     16,384
  u32*   flag  = (u32*)(ws + 107495424ull);    //        256
  u16*   svec  = (u16*)(ws + 107495680ull);    //     52,096 packed small vectors
  u16*   cw_b  = svec;                         // conv_w  17408
  u16*   cb_b  = svec + 17408;                 // conv_b   4352
  u16*   al_b  = svec + 21760;                 // A_log      64
  u16*   d_b   = svec + 21824;                 // D          64
  u16*   db_b  = svec + 21888;                 // dt_bias    64
  u16*   nw_b  = svec + 21952;                 // norm_w   4096
  u16*   S     = (u16*)(ws + 107626496ull);    // 67,108,864 -> end 174,735,360
  u16*   hb    = (u16*)(ws + 107626496ull);    // 16,777,216 overlays S (early)
  u16*   w1b   = (u16*)(ws + 124403712ull);    // 35,651,584 overlays S (early) [8704][2048] = in_proj^T padded -> end 160,055,296
  u16*   g     = (u16*)(ws + 107626496ull);    // 33,554,432 overlays S (late)

  // 0) dtype detect + canonicalize to bf16 (weights transposed for GEMM)
  detect_kernel<<<1, 256, 0, stream>>>(hidden_r, flag);
  cvt_kernel<<<4096, 256, 0, stream>>>(hidden_r, hb, 8388608, flag);
  cvt_transpose_kernel<<<dim3(136, 32), 256, 0, stream>>>(
      in_proj_r, w1b, 2048, 8512, 8704, flag);
  cvt_small_kernel<<<102, 256, 0, stream>>>(conv_w_r, conv_b_r, A_log_r,
      Dvec_r, dt_bias_r, norm_w_r, svec, flag);
  // 1) GEMM1: split epilogue -> z / xbcr / dtraw  (M=4096, Npad=8704, K=2048)
  gemm_kernel<<<dim3(34, 16), 512, 0, stream>>>(
      hb, w1b, z, xbcr, dtraw, (float*)nullptr, 4096, 8704, 2048, 1);
  // 2) conv + silu (0.5 mup folded)
  conv_silu_kernel<<<dim3(17, 4096), 256, 0, stream>>>(xbcr, cw_b, cb_b, xbc);
  // 3) dt softplus + log-decays
  dt_kernel<<<1024, 256, 0, stream>>>(dtraw, db_b, al_b, dt_s, lda);
  chunk_decay_kernel<<<16, 256, 0, stream>>>(lda, cdexp);
  // 4) SSD chunked scan (validated against exact scan in r4)
  ssd_intra_kernel<<<dim3(NCHUNK, 64, 2), 256, 0, stream>>>(xbc, dt_s, lda, S, yb);
  ssd_carry_kernel<<<4096, 256, 0, stream>>>(S, cdexp);
  ssd_inter_kernel<<<dim3(NCHUNK, 64, 2), 256, 0, stream>>>(xbc, lda, S, d_b, yb);
  // 5) late transpose-conversion of out_proj into xbc's slot (xbc dead after inter)
  cvt_transpose_kernel<<<dim3(32, 64), 256, 0, stream>>>(
      out_proj_r, w2b, 4096, 2048, 2048, flag);
  // 6) RMSNorm + silu(0.25*z) gate (g overlays S)
  rmsnorm_gate_kernel<<<4096, 256, 0, stream>>>(yb, z, nw_b, g);
  // 7) GEMM2: out = g @ out_proj  (M=4096, N=2048, K=4096) -> fp32 out
  gemm_kernel<<<dim3(8, 16), 512, 0, stream>>>(
      g, w2b, (u16*)nullptr, (u16*)nullptr, (u16*)nullptr, out,
      4096, 2048, 4096, 2);
}

// Round 4
// 711.680 us; speedup vs baseline: 1.9485x; 1.0099x over previous
//
#include <hip/hip_runtime.h>
#include <stdint.h>

typedef unsigned short u16;
typedef unsigned int   u32;
typedef __attribute__((ext_vector_type(8))) short bf16x8;
typedef __attribute__((ext_vector_type(4))) float f32x4;
typedef __attribute__((ext_vector_type(4))) u32   u32x4;

static __device__ __forceinline__ float bf2f(u16 v){
  u32 u = ((u32)v) << 16;
  return __builtin_bit_cast(float, u);
}
static __device__ __forceinline__ u16 f2bf(float f){
  u32 u = __builtin_bit_cast(u32, f);
  return (u16)((u + 0x7fffu + ((u >> 16) & 1u)) >> 16);
}

#define MFMA16(a,b,c) __builtin_amdgcn_mfma_f32_16x16x32_bf16((a),(b),(c),0,0,0)

// async global->LDS, 16B per lane (emits global_load_lds_dwordx4)
typedef const __attribute__((address_space(1))) char glb_c;
typedef __attribute__((address_space(3))) char lds_c;
static __device__ __forceinline__ void gload_lds16(const void* g, void* l){
  __builtin_amdgcn_global_load_lds((glb_c*)g, (lds_c*)l, 16, 0, 0);
}

// Model dims
#define SEQN   2048
#define PROJD  8512
#define CONVD  4352
#define INTERD 4096
#define NST    128
#define QC     64
#define NCHUNK 32

// ---------------------------------------------------------------------------
// Input dtype detection (fp32 confirmed; kept for robustness).
__global__ __launch_bounds__(256) void detect_kernel(
    const void* __restrict__ hidden, u32* __restrict__ flag)
{
  __shared__ int cnt;
  if (threadIdx.x == 0) cnt = 0;
  __syncthreads();
  if (threadIdx.x < 128){
    u16 v = ((const u16*)hidden)[threadIdx.x * 2];
    int e = (v >> 7) & 0xFF;
    int plaus = (v == 0) || (e >= 0x70 && e <= 0x8F);
    atomicAdd(&cnt, plaus);
  }
  __syncthreads();
  if (threadIdx.x == 0) *flag = (cnt < 64) ? 1u : 0u;   // 1 = fp32 inputs
}

__global__ __launch_bounds__(256) void cvt_kernel(
    const void* __restrict__ src, u16* __restrict__ dst, int n,
    const u32* __restrict__ flag)
{
  bool isf32 = (*flag != 0);
  int stride = gridDim.x * 256;
  for (int i = blockIdx.x*256 + threadIdx.x; i < n; i += stride){
    if (isf32) dst[i] = f2bf(((const float*)src)[i]);
    else       dst[i] = ((const u16*)src)[i];
  }
}

// Convert + transpose weights: src [K][N] (fp32 or bf16) -> dst [Npad][K] bf16.
// Rows n >= N are zero-filled (pad for tile-exact GEMM).
__global__ __launch_bounds__(256) void cvt_transpose_kernel(
    const void* __restrict__ src, u16* __restrict__ dst,
    int K, int N, int Npad, const u32* __restrict__ flag)
{
  bool isf32 = (*flag != 0);
  __shared__ u16 tile[64][72];
  int n0 = blockIdx.x * 64, k0 = blockIdx.y * 64;
  int tid = threadIdx.x;
  int tr = tid >> 6;     // wave id 0..3
  int tc = tid & 63;
  #pragma unroll
  for (int i = 0; i < 16; i++){
    int k = i*4 + tr;
    int gk = k0 + k, gn = n0 + tc;
    float v = 0.f;
    if (gk < K && gn < N)
      v = isf32 ? ((const float*)src)[(size_t)gk*N + gn]
                : bf2f(((const u16*)src)[(size_t)gk*N + gn]);
    tile[k][tc] = f2bf(v);
  }
  __syncthreads();
  #pragma unroll
  for (int i = 0; i < 16; i++){
    int n = i*4 + tr;
    int gn = n0 + n;
    if (gn < Npad && (k0 + tc) < K)
      dst[(size_t)gn*K + k0 + tc] = tile[tc][n];
  }
}

__global__ __launch_bounds__(256) void cvt_small_kernel(
    const void* cw, const void* cb, const void* al, const void* dv,
    const void* db, const void* nw, u16* __restrict__ base,
    const u32* __restrict__ flag)
{
  bool isf32 = (*flag != 0);
  int idx = blockIdx.x*256 + threadIdx.x;   // 0 .. 26047
  if (idx >= 26048) return;
  const void* src; int off;
  if      (idx < 17408){ src = cw; off = idx;          }
  else if (idx < 21760){ src = cb; off = idx - 17408;  }
  else if (idx < 21824){ src = al; off = idx - 21760;  }
  else if (idx < 21888){ src = dv; off = idx - 21824;  }
  else if (idx < 21952){ src = db; off = idx - 21888;  }
  else                 { src = nw; off = idx - 21952;  }
  u16 v = isf32 ? f2bf(((const float*)src)[off]) : ((const u16*)src)[off];
  base[idx] = v;
}

// ---------------------------------------------------------------------------
// C = A[M,K] @ Bt[N,K]^T (row-major bf16, B pre-transposed), fp32 MFMA accum.
// Tile (MT*128)x256, BK=64, 512 threads (8 waves, 2Mx4N), LDS double-buffer.
// 8-phase counted-vmcnt schedule, ONE barrier per phase:
//   phase p: {ds_read frags | stage 1 half-tile | (vmcnt gate) | barrier |
//             setprio(1) MFMA setprio(0)}
// Wave slippage after MFMA issue overlaps next phase's LDS reads with the
// draining matrix pipe (no post-MFMA barrier). WAR safety: every stage
// targets a region whose last reader drained it (compiler lgkmcnt before its
// MFMA) >=2 barriers earlier; barrier skew <=1 phase. RAW safety: vmcnt(4)
// gates at p3/p7 retire the next buffer's loads before its first read.
// Ledger (1 B-half = 2 loads, 1 A-half = MT loads); enter iter with 4 (B odd):
//   p0+A p1+A p2+B p3+B -> gate vmcnt(4); p4+A p5+A p6+B p7+B -> vmcnt(4)
// (works out to the same constants for MT=1 and MT=2). Last iter: vmcnt(0).
// Requires: M%(MT*128)==0, N%256==0 (pad), K%128==0, nwg%8==0.
template<int MT>
__global__ __launch_bounds__(512, 2) void gemm_kernel(
    const u16* __restrict__ A, const u16* __restrict__ Bt,
    u16* __restrict__ C0, u16* __restrict__ C1, u16* __restrict__ C2,
    float* __restrict__ CF,
    int M, int N, int K, int mode)
{
  constexpr int ASZ  = MT * 16384;        // A bytes per buffer
  constexpr int BUFS = ASZ + 32768;       // buffer stride (A|B)
  __shared__ u16 smem[BUFS];              // *2 bytes = 2 buffers total

  const int nbx = gridDim.x;
  const int nwg = nbx * gridDim.y;
  const int bid = blockIdx.y * nbx + blockIdx.x;
  const int swz = (bid & 7) * (nwg >> 3) + (bid >> 3);
  const int m0 = (swz / nbx) * (MT*128), n0 = (swz % nbx) * 256;

  const int tid = threadIdx.x;
  const int wave = tid >> 6, lane = tid & 63;
  const int l15 = lane & 15, quad = lane >> 4;
  const int wm = wave >> 2, wn = wave & 3;   // 2 x 4 wave grid

  // staging: thread covers row (tid>>3) of each 64-row group, chunk (tid&7);
  // global source chunk XOR-swizzled, LDS write linear (both-sides rule).
  const size_t Kb = (size_t)K * 2;
  const int srow = tid >> 3;
  const int schk = (tid & 7) ^ (srow & 7);
  const char* Abp = (const char*)A  + (size_t)(m0 + srow) * Kb + schk * 16;
  const char* Bbp = (const char*)Bt + (size_t)(n0 + srow) * Kb + schk * 16;
  char* ldsb = (char*)smem + wave * 1024;   // wave-uniform; HW adds lane*16

  // ds_read bases per [buffer][kk2]; fragment row offset folds to immediate.
  const int aoff0 = ((quad    ) ^ (l15 & 7)) << 4;
  const int aoff1 = ((quad + 4) ^ (l15 & 7)) << 4;
  const char* ardb[2][2];
  const char* brdb[2][2];
  #pragma unroll
  for (int c = 0; c < 2; c++){
    ardb[c][0] = (const char*)smem + c*BUFS + (wm*(MT*64) + l15)*128 + aoff0;
    ardb[c][1] = (const char*)smem + c*BUFS + (wm*(MT*64) + l15)*128 + aoff1;
    brdb[c][0] = (const char*)smem + c*BUFS + ASZ + (wn*64 + l15)*128 + aoff0;
    brdb[c][1] = (const char*)smem + c*BUFS + ASZ + (wn*64 + l15)*128 + aoff1;
  }

  f32x4 acc[MT*4][4];
  #pragma unroll
  for (int i = 0; i < MT*4; i++)
    #pragma unroll
    for (int j = 0; j < 4; j++) acc[i][j] = (f32x4){0.f,0.f,0.f,0.f};

  bf16x8 af[2*MT];   // A frags for current phase quadrant: [mf2*2+kk2]
  bf16x8 bfr[8];     // B frags for current tile: [nf*2+kk2]

#define STGB(par, h, kt) do{                                             \
    const char* _s = Bbp + (size_t)((h)*128)*Kb + (size_t)(kt)*128;      \
    char* _d = ldsb + (par)*BUFS + ASZ + (h)*16384;                      \
    gload_lds16(_s, _d);                                                 \
    gload_lds16(_s + 64*Kb, _d + 8192);                                  \
  }while(0)
#define STGA(par, h, kt) do{                                             \
    const char* _s = Abp + (size_t)((h)*(MT*64))*Kb + (size_t)(kt)*128;  \
    char* _d = ldsb + (par)*BUFS + (h)*(MT*8192);                        \
    gload_lds16(_s, _d);                                                 \
    if (MT == 2) gload_lds16(_s + 64*Kb, _d + 8192);                     \
  }while(0)

  // ---- prologue: stage T0 fully + B(T1); keep B(T1) in flight
  STGB(0,0,0); STGB(0,1,0);
  STGA(0,0,0); STGA(0,1,0);
  STGB(1,0,1); STGB(1,1,1);
  asm volatile("s_waitcnt vmcnt(4)" ::: "memory");
  __builtin_amdgcn_s_barrier();

  const int NT = K >> 6;
  for (int I = 0; I < (NT >> 1); ++I){
    const int T1 = 2*I+1, T2 = 2*I+2, T3 = 2*I+3;
    const bool pf = (T2 < NT);
    #pragma unroll
    for (int p = 0; p < 8; ++p){
      const int q = p & 3, c = p >> 2;   // quadrant, buffer/tile parity
      // 1) ds_read THIS phase's fragments (A quadrant q; B of tile if q==0)
      #pragma unroll
      for (int k = 0; k < 2; k++)
        #pragma unroll
        for (int mf2 = 0; mf2 < MT; mf2++)
          af[mf2*2+k] = *(const bf16x8*)(ardb[c][k] + (MT*q+mf2)*2048);
      if (q == 0){
        #pragma unroll
        for (int nf = 0; nf < 4; nf++)
          #pragma unroll
          for (int k = 0; k < 2; k++)
            bfr[nf*2+k] = *(const bf16x8*)(brdb[c][k] + nf*2048);
      }
      // 2) stage one half-tile; 3) counted vmcnt gates at p3/p7
      if      (p == 0) STGA(1,0,T1);
      else if (p == 1) STGA(1,1,T1);
      else if (p == 2){ if (pf) STGB(0,0,T2); }
      else if (p == 3){
        if (pf){ STGB(0,1,T2);
                 asm volatile("s_waitcnt vmcnt(4)" ::: "memory"); }
        else     asm volatile("s_waitcnt vmcnt(0)" ::: "memory");
      }
      else if (p == 4){ if (pf) STGA(0,0,T2); }
      else if (p == 5){ if (pf) STGA(0,1,T2); }
      else if (p == 6){ if (pf) STGB(1,0,T3); }
      else            { if (pf){ STGB(1,1,T3);
                 asm volatile("s_waitcnt vmcnt(4)" ::: "memory"); } }
      asm volatile("" ::: "memory");
      __builtin_amdgcn_s_barrier();
      // 4) MFMA: quadrant q of tile in buffer c (compiler inserts counted
      //    lgkmcnt before first use; no post-MFMA barrier -> wave slippage
      //    overlaps next phase's LDS reads with the draining matrix pipe)
      __builtin_amdgcn_s_setprio(1);
      #pragma unroll
      for (int mf2 = 0; mf2 < MT; ++mf2)
        #pragma unroll
        for (int nf = 0; nf < 4; ++nf)
          #pragma unroll
          for (int k = 0; k < 2; k++)
            acc[MT*q+mf2][nf] =
                MFMA16(af[mf2*2+k], bfr[nf*2+k], acc[MT*q+mf2][nf]);
      __builtin_amdgcn_s_setprio(0);
    }
  }
#undef STGA
#undef STGB

  // ---- epilogue
  #pragma unroll
  for (int nf = 0; nf < 4; nf++){
    int col = n0 + wn*64 + nf*16 + l15;
    #pragma unroll
    for (int mf = 0; mf < MT*4; mf++){
      #pragma unroll
      for (int r = 0; r < 4; r++){
        int row = m0 + wm*(MT*64) + mf*16 + quad*4 + r;
        float fv = acc[mf][nf][r];
        if (mode == 2){
          if (col < N) CF[(size_t)row*N + col] = fv;
        } else if (mode == 0){
          if (col < N) C0[(size_t)row*N + col] = f2bf(fv);
        } else {
          u16 v = f2bf(fv);
          if      (col < 4096) C0[(size_t)row*4096 + col] = v;
          else if (col < 8448) C1[(size_t)row*CONVD + (col - 4096)] = v;
          else if (col < 8512) C2[(size_t)row*64 + (col - 8448)] = v;
          // cols 8512..8703 are zero-padding, dropped
        }
      }
    }
  }
}

// ---------------------------------------------------------------------------
// Causal depthwise conv (K=4, left pad 3) + bias + silu; 0.5 mup folded.
__global__ __launch_bounds__(256) void conv_silu_kernel(
    const u16* __restrict__ xbcr, const u16* __restrict__ conv_w,
    const u16* __restrict__ conv_b, u16* __restrict__ xbc)
{
  int c  = blockIdx.x * 256 + threadIdx.x;   // 17*256 = 4352 exact
  int rl = blockIdx.y;
  int b = rl >> 11, l = rl & 2047;
  float w[4];
  #pragma unroll
  for (int k=0;k<4;k++) w[k] = 0.5f * bf2f(conv_w[c*4 + k]);
  float acc = bf2f(conv_b[c]);
  #pragma unroll
  for (int k=0;k<4;k++){
    int s = l + k - 3;
    if (s >= 0) acc += bf2f(xbcr[(size_t)(b*2048 + s)*CONVD + c]) * w[k];
  }
  float sig = 1.f / (1.f + __expf(-acc));
  xbc[(size_t)rl*CONVD + c] = f2bf(acc * sig);
}

// ---------------------------------------------------------------------------
// dt_soft = softplus(dtraw + dt_bias); ldA = dt_soft * (-exp(A_log)).
__global__ __launch_bounds__(256) void dt_kernel(
    const u16* __restrict__ dtraw, const u16* __restrict__ dt_bias,
    const u16* __restrict__ A_log, float* __restrict__ dt_soft,
    float* __restrict__ ldA)
{
  int idx = blockIdx.x * 256 + threadIdx.x;  // 4096*64
  int h = idx & 63;
  float x = bf2f(dtraw[idx]) + bf2f(dt_bias[h]);
  float sp = (x > 20.f) ? x : log1pf(expf(x));
  float A = -expf(bf2f(A_log[h]));
  dt_soft[idx] = sp;
  ldA[idx] = sp * A;
}

__global__ __launch_bounds__(256) void chunk_decay_kernel(
    const float* __restrict__ ldA, float* __restrict__ cdexp)
{
  int idx = blockIdx.x * 256 + threadIdx.x;  // 4096
  int q = idx & 31, bh = idx >> 5;
  int b = bh >> 6, h = bh & 63;
  float s = 0.f;
  int t0 = q * QC;
  for (int t = 0; t < QC; t++) s += ldA[(size_t)(b*2048 + t0 + t)*64 + h];
  cdexp[idx] = expf(s);
}

// ---------------------------------------------------------------------------
// SSD intra-chunk (validated in r4 bisection: matches exact scan).
#define SBS  136
#define SUTS 80
#define SMS  80
__global__ __launch_bounds__(256) void ssd_intra_kernel(
    const u16* __restrict__ xbc, const float* __restrict__ dt_soft,
    const float* __restrict__ ldA, u16* __restrict__ S,
    u16* __restrict__ y)
{
  int q = blockIdx.x, h = blockIdx.y, b = blockIdx.z;
  int bh = b*64 + h;
  int t0 = q * QC;
  int tid = threadIdx.x, wave = tid >> 6, lane = tid & 63;
  int l15 = lane & 15, quad = lane >> 4;

  __shared__ u16 sB [64*SBS];
  __shared__ u16 sCM[64*SBS];
  __shared__ u16 sBt[128*64];
  __shared__ u16 sUt[64*SUTS];
  __shared__ float sLa[64];
  __shared__ float sW[64];

  if (tid < 64){
    float v = ldA[(size_t)(b*2048 + t0 + tid)*64 + h];
    #pragma unroll
    for (int off = 1; off < 64; off <<= 1){
      float o = __shfl_up(v, off, 64);
      if (lane >= off) v += o;
    }
    sLa[tid] = v;
  }
  __syncthreads();
  float laE = sLa[63];
  if (tid < 64) sW[tid] = __expf(laE - sLa[tid]);
  __syncthreads();

  #pragma unroll
  for (int i = 0; i < 4; i++){
    int ch = i*256 + tid;
    int s = ch >> 4, nc = (ch & 15) * 8;
    const u16* src = xbc + (size_t)(b*2048 + t0 + s)*CONVD;
    u32x4 vb = *(const u32x4*)(src + 4096 + nc);
    u32x4 vc = *(const u32x4*)(src + 4224 + nc);
    *(u32x4*)(sB  + s*SBS + nc) = vb;
    *(u32x4*)(sCM + s*SBS + nc) = vc;
    float wdec = sW[s];
    const u16* pb = (const u16*)&vb;
    #pragma unroll
    for (int e = 0; e < 8; e++)
      sBt[(nc + e)*64 + s] = f2bf(bf2f(pb[e]) * wdec);
  }
  #pragma unroll
  for (int i = 0; i < 2; i++){
    int ch = i*256 + tid;
    int s = ch >> 3, pc = (ch & 7) * 8;
    const u16* src = xbc + (size_t)(b*2048 + t0 + s)*CONVD + h*64 + pc;
    u32x4 vx = *(const u32x4*)src;
    float dt = dt_soft[(size_t)(b*2048 + t0 + s)*64 + h];
    const u16* px = (const u16*)&vx;
    #pragma unroll
    for (int e = 0; e < 8; e++)
      sUt[(pc + e)*SUTS + s] = f2bf(bf2f(px[e]) * dt);
  }
  __syncthreads();

  // MFMA1: M[t][s] = sum_n C[t][n]*B[s][n]
  int tr = (wave & 1)*32, sc = (wave >> 1)*32;
  f32x4 aM[2][2];
  #pragma unroll
  for (int i=0;i<2;i++)
    #pragma unroll
    for (int j=0;j<2;j++) aM[i][j] = (f32x4){0.f,0.f,0.f,0.f};
  #pragma unroll
  for (int kk = 0; kk < 128; kk += 32){
    bf16x8 a0 = *(const bf16x8*)(sCM + (tr      + l15)*SBS + kk + quad*8);
    bf16x8 a1 = *(const bf16x8*)(sCM + (tr + 16 + l15)*SBS + kk + quad*8);
    bf16x8 b0 = *(const bf16x8*)(sB  + (sc      + l15)*SBS + kk + quad*8);
    bf16x8 b1 = *(const bf16x8*)(sB  + (sc + 16 + l15)*SBS + kk + quad*8);
    aM[0][0] = MFMA16(a0, b0, aM[0][0]);
    aM[0][1] = MFMA16(a0, b1, aM[0][1]);
    aM[1][0] = MFMA16(a1, b0, aM[1][0]);
    aM[1][1] = MFMA16(a1, b1, aM[1][1]);
  }
  __syncthreads();
  u16* sM = sCM;
  #pragma unroll
  for (int i = 0; i < 2; i++){
    #pragma unroll
    for (int j = 0; j < 2; j++){
      int scol = sc + j*16 + l15;
      #pragma unroll
      for (int r = 0; r < 4; r++){
        int trow = tr + i*16 + quad*4 + r;
        float v = 0.f;
        if (scol <= trow) v = aM[i][j][r] * __expf(sLa[trow] - sLa[scol]);
        sM[trow*SMS + scol] = f2bf(v);
      }
    }
  }
  __syncthreads();

  // MFMA2: Y[t][p] = sum_s M[t][s]*u[s][p]
  f32x4 aY[2][2];
  #pragma unroll
  for (int i=0;i<2;i++)
    #pragma unroll
    for (int j=0;j<2;j++) aY[i][j] = (f32x4){0.f,0.f,0.f,0.f};
  #pragma unroll
  for (int kk = 0; kk < 64; kk += 32){
    bf16x8 a0 = *(const bf16x8*)(sM  + (tr      + l15)*SMS  + kk + quad*8);
    bf16x8 a1 = *(const bf16x8*)(sM  + (tr + 16 + l15)*SMS  + kk + quad*8);
    bf16x8 b0 = *(const bf16x8*)(sUt + (sc      + l15)*SUTS + kk + quad*8);
    bf16x8 b1 = *(const bf16x8*)(sUt + (sc + 16 + l15)*SUTS + kk + quad*8);
    aY[0][0] = MFMA16(a0, b0, aY[0][0]);
    aY[0][1] = MFMA16(a0, b1, aY[0][1]);
    aY[1][0] = MFMA16(a1, b0, aY[1][0]);
    aY[1][1] = MFMA16(a1, b1, aY[1][1]);
  }
  #pragma unroll
  for (int i = 0; i < 2; i++){
    #pragma unroll
    for (int j = 0; j < 2; j++){
      int p = sc + j*16 + l15;
      #pragma unroll
      for (int r = 0; r < 4; r++){
        int t = tr + i*16 + quad*4 + r;
        y[(size_t)(b*2048 + t0 + t)*INTERD + h*64 + p] = f2bf(aY[i][j][r]);
      }
    }
  }

  // MFMA3: S[p][n] = sum_s u[s][p]*decay(s)*B[s][n]
  int pr = (wave & 1)*32, nw = (wave >> 1)*64;
  f32x4 aS[2][4];
  #pragma unroll
  for (int i=0;i<2;i++)
    #pragma unroll
    for (int j=0;j<4;j++) aS[i][j] = (f32x4){0.f,0.f,0.f,0.f};
  #pragma unroll
  for (int kk = 0; kk < 64; kk += 32){
    bf16x8 a0 = *(const bf16x8*)(sUt + (pr      + l15)*SUTS + kk + quad*8);
    bf16x8 a1 = *(const bf16x8*)(sUt + (pr + 16 + l15)*SUTS + kk + quad*8);
    #pragma unroll
    for (int j = 0; j < 4; j++){
      bf16x8 bb = *(const bf16x8*)(sBt + (nw + j*16 + l15)*64 + kk + quad*8);
      aS[0][j] = MFMA16(a0, bb, aS[0][j]);
      aS[1][j] = MFMA16(a1, bb, aS[1][j]);
    }
  }
  u16* Sl = S + ((size_t)bh*NCHUNK + q)*8192;
  #pragma unroll
  for (int i = 0; i < 2; i++){
    #pragma unroll
    for (int j = 0; j < 4; j++){
      int n = nw + j*16 + l15;
      #pragma unroll
      for (int r = 0; r < 4; r++){
        int p = pr + i*16 + quad*4 + r;
        Sl[p*NST + n] = f2bf(aS[i][j][r]);
      }
    }
  }
}

// ---------------------------------------------------------------------------
// Inter-chunk recurrence, in-place.
__global__ __launch_bounds__(256) void ssd_carry_kernel(
    u16* __restrict__ S, const float* __restrict__ cdexp)
{
  int idx = blockIdx.x * 256 + threadIdx.x;   // 2*64*8192
  int e = idx & 8191, bh = idx >> 13;
  float E = 0.f;
  for (int q = 0; q < NCHUNK; q++){
    size_t off = ((size_t)bh*NCHUNK + q)*8192 + e;
    float v = bf2f(S[off]);
    S[off] = f2bf(E);
    E = cdexp[bh*NCHUNK + q] * E + v;
  }
}

// ---------------------------------------------------------------------------
// Inter-chunk output: y += exp(la[t]) * C_t @ S_q^T + D*x
__global__ __launch_bounds__(256) void ssd_inter_kernel(
    const u16* __restrict__ xbc, const float* __restrict__ ldA,
    const u16* __restrict__ S, const u16* __restrict__ Dvec,
    u16* __restrict__ y)
{
  int q = blockIdx.x, h = blockIdx.y, b = blockIdx.z;
  int bh = b*64 + h;
  int t0 = q * QC;
  int tid = threadIdx.x, wave = tid >> 6, lane = tid & 63;
  int l15 = lane & 15, quad = lane >> 4;

  __shared__ u16 sC[64*SBS];
  __shared__ u16 sS[64*SBS];
  __shared__ float sLa[64];

  if (tid < 64){
    float v = ldA[(size_t)(b*2048 + t0 + tid)*64 + h];
    #pragma unroll
    for (int off = 1; off < 64; off <<= 1){
      float o = __shfl_up(v, off, 64);
      if (lane >= off) v += o;
    }
    sLa[tid] = v;
  }
  const u16* Sc = S + ((size_t)bh*NCHUNK + q)*8192;
  #pragma unroll
  for (int i = 0; i < 4; i++){
    int ch = i*256 + tid;
    int s = ch >> 4, nc = (ch & 15) * 8;
    *(u32x4*)(sC + s*SBS + nc) =
        *(const u32x4*)(xbc + (size_t)(b*2048 + t0 + s)*CONVD + 4224 + nc);
    *(u32x4*)(sS + s*SBS + nc) = *(const u32x4*)(Sc + s*NST + nc);
  }
  __syncthreads();

  int tr = (wave & 1)*32, pc = (wave >> 1)*32;
  f32x4 acc[2][2];
  #pragma unroll
  for (int i=0;i<2;i++)
    #pragma unroll
    for (int j=0;j<2;j++) acc[i][j] = (f32x4){0.f,0.f,0.f,0.f};
  #pragma unroll
  for (int kk = 0; kk < 128; kk += 32){
    bf16x8 a0 = *(const bf16x8*)(sC + (tr      + l15)*SBS + kk + quad*8);
    bf16x8 a1 = *(const bf16x8*)(sC + (tr + 16 + l15)*SBS + kk + quad*8);
    bf16x8 b0 = *(const bf16x8*)(sS + (pc      + l15)*SBS + kk + quad*8);
    bf16x8 b1 = *(const bf16x8*)(sS + (pc + 16 + l15)*SBS + kk + quad*8);
    acc[0][0] = MFMA16(a0, b0, acc[0][0]);
    acc[0][1] = MFMA16(a0, b1, acc[0][1]);
    acc[1][0] = MFMA16(a1, b0, acc[1][0]);
    acc[1][1] = MFMA16(a1, b1, acc[1][1]);
  }
  float Dh = bf2f(Dvec[h]);
  #pragma unroll
  for (int i = 0; i < 2; i++){
    #pragma unroll
    for (int j = 0; j < 2; j++){
      int p = pc + j*16 + l15;
      #pragma unroll
      for (int r = 0; r < 4; r++){
        int t = tr + i*16 + quad*4 + r;
        size_t row = (size_t)(b*2048 + t0 + t);
        size_t yo = row*INTERD + h*64 + p;
        float xv = bf2f(xbc[row*CONVD + h*64 + p]);
        float v = bf2f(y[yo]) + __expf(sLa[t]) * acc[i][j][r] + Dh * xv;
        y[yo] = f2bf(v);
      }
    }
  }
}

// ---------------------------------------------------------------------------
// RMSNorm * norm_w, gated by silu(0.25*z).
__global__ __launch_bounds__(256) void rmsnorm_gate_kernel(
    const u16* __restrict__ y, const u16* __restrict__ z,
    const u16* __restrict__ norm_w, u16* __restrict__ g)
{
  int rl = blockIdx.x;
  int tid = threadIdx.x, wave = tid >> 6, lane = tid & 63;
  const u16* yr = y + (size_t)rl*INTERD;
  float vy[16];
  float ss = 0.f;
  #pragma unroll
  for (int i = 0; i < 16; i++){
    int idx = i*256 + tid;
    float v = bf2f(yr[idx]);
    vy[i] = v;
    ss += v*v;
  }
  #pragma unroll
  for (int off = 32; off >= 1; off >>= 1) ss += __shfl_xor(ss, off, 64);
  __shared__ float red[4];
  if (lane == 0) red[wave] = ss;
  __syncthreads();
  float tot = red[0] + red[1] + red[2] + red[3];
  float rstd = rsqrtf(tot * (1.f/4096.f) + 1e-5f);
  const u16* zr = z + (size_t)rl*INTERD;
  u16* gr = g + (size_t)rl*INTERD;
  #pragma unroll
  for (int i = 0; i < 16; i++){
    int idx = i*256 + tid;
    float v = vy[i] * rstd * bf2f(norm_w[idx]);
    float zv = 0.25f * bf2f(zr[idx]);
    float sig = 1.f / (1.f + __expf(-zv));
    gr[idx] = f2bf(v * zv * sig);
  }
}

// ---------------------------------------------------------------------------
extern "C" void kernel_launch(void* const* d_in, const int* in_sizes, int n_in,
                              void* d_out, int out_size, void* d_ws, size_t ws_size,
                              hipStream_t stream)
{
  const void* hidden_r    = d_in[0];
  const void* in_proj_r   = d_in[1];
  const void* conv_w_r    = d_in[2];
  const void* conv_b_r    = d_in[3];
  const void* A_log_r     = d_in[4];
  const void* Dvec_r      = d_in[5];
  const void* dt_bias_r   = d_in[6];
  const void* norm_w_r    = d_in[7];
  const void* out_proj_r  = d_in[8];
  float* out = (float*)d_out;          // reference output dtype = float32
  char* ws = (char*)d_ws;

  // workspace layout (bytes); peak = 174,735,360 (proven in-bounds in r3)
  u16*   z     = (u16*)(ws + 0);               // 33,554,432
  u16*   xbcr  = (u16*)(ws + 33554432ull);     // 35,651,584 (dead after conv)
  u16*   yb    = (u16*)(ws + 33554432ull);     // 33,554,432 overlays xbcr
  u16*   dtraw = (u16*)(ws + 69206016ull);     //    524,288
  u16*   xbc   = (u16*)(ws + 69730304ull);     // 35,651,584 (dead after inter)
  u16*   w2b   = (u16*)(ws + 69730304ull);     // 16,777,216 overlays xbc (late)  [2048][4096] = out_proj^T
  float* dt_s  = (float*)(ws + 105381888ull);  //  1,048,576
  float* lda   = (float*)(ws + 106430464ull);  //  1,048,576
  float* cdexp = (float*)(ws + 107479040ull);  //     16,384
  u32*   flag  = (u32*)(ws + 107495424ull);    //        256
  u16*   svec  = (u16*)(ws + 107495680ull);    //     52,096 packed small vectors
  u16*   cw_b  = svec;                         // conv_w  17408
  u16*   cb_b  = svec + 17408;                 // conv_b   4352
  u16*   al_b  = svec + 21760;                 // A_log      64
  u16*   d_b   = svec + 21824;                 // D          64
  u16*   db_b  = svec + 21888;                 // dt_bias    64
  u16*   nw_b  = svec + 21952;                 // norm_w   4096
  u16*   S     = (u16*)(ws + 107626496ull);    // 67,108,864 -> end 174,735,360
  u16*   hb    = (u16*)(ws + 107626496ull);    // 16,777,216 overlays S (early)
  u16*   w1b   = (u16*)(ws + 124403712ull);    // 35,651,584 overlays S (early) [8704][2048] = in_proj^T padded -> end 160,055,296
  u16*   g     = (u16*)(ws + 107626496ull);    // 33,554,432 overlays S (late)

  // 0) dtype detect + canonicalize to bf16 (weights transposed for GEMM)
  detect_kernel<<<1, 256, 0, stream>>>(hidden_r, flag);
  cvt_kernel<<<4096, 256, 0, stream>>>(hidden_r, hb, 8388608, flag);
  cvt_transpose_kernel<<<dim3(136, 32), 256, 0, stream>>>(
      in_proj_r, w1b, 2048, 8512, 8704, flag);
  cvt_small_kernel<<<102, 256, 0, stream>>>(conv_w_r, conv_b_r, A_log_r,
      Dvec_r, dt_bias_r, norm_w_r, svec, flag);
  // 1) GEMM1: split epilogue -> z / xbcr / dtraw  (M=4096, Npad=8704, K=2048)
  gemm_kernel<2><<<dim3(34, 16), 512, 0, stream>>>(
      hb, w1b, z, xbcr, dtraw, (float*)nullptr, 4096, 8704, 2048, 1);
  // 2) conv + silu (0.5 mup folded)
  conv_silu_kernel<<<dim3(17, 4096), 256, 0, stream>>>(xbcr, cw_b, cb_b, xbc);
  // 3) dt softplus + log-decays
  dt_kernel<<<1024, 256, 0, stream>>>(dtraw, db_b, al_b, dt_s, lda);
  chunk_decay_kernel<<<16, 256, 0, stream>>>(lda, cdexp);
  // 4) SSD chunked scan (validated against exact scan in r4)
  ssd_intra_kernel<<<dim3(NCHUNK, 64, 2), 256, 0, stream>>>(xbc, dt_s, lda, S, yb);
  ssd_carry_kernel<<<4096, 256, 0, stream>>>(S, cdexp);
  ssd_inter_kernel<<<dim3(NCHUNK, 64, 2), 256, 0, stream>>>(xbc, lda, S, d_b, yb);
  // 5) late transpose-conversion of out_proj into xbc's slot (xbc dead after inter)
  cvt_transpose_kernel<<<dim3(32, 64), 256, 0, stream>>>(
      out_proj_r, w2b, 4096, 2048, 2048, flag);
  // 6) RMSNorm + silu(0.25*z) gate (g overlays S)
  rmsnorm_gate_kernel<<<4096, 256, 0, stream>>>(yb, z, nw_b, g);
  // 7) GEMM2: out = g @ out_proj  (M=4096, N=2048, K=4096) -> fp32 out
  //    MT=1 (128x256 tile): grid 8x32 = 256 blocks = exactly 1/CU.
  gemm_kernel<1><<<dim3(8, 32), 512, 0, stream>>>(
      g, w2b, (u16*)nullptr, (u16*)nullptr, (u16*)nullptr, out,
      4096, 2048, 4096, 2);
}

// Round 6
// 656.581 us; speedup vs baseline: 2.1120x; 1.0839x over previous
//
#include <hip/hip_runtime.h>
#include <stdint.h>

typedef unsigned short u16;
typedef unsigned int   u32;
typedef __attribute__((ext_vector_type(8))) short bf16x8;
typedef __attribute__((ext_vector_type(4))) short s16x4;
typedef __attribute__((ext_vector_type(4))) float f32x4;
typedef __attribute__((ext_vector_type(4))) u32   u32x4;

static __device__ __forceinline__ float bf2f(u16 v){
  u32 u = ((u32)v) << 16;
  return __builtin_bit_cast(float, u);
}
static __device__ __forceinline__ u16 f2bf(float f){
  u32 u = __builtin_bit_cast(u32, f);
  return (u16)((u + 0x7fffu + ((u >> 16) & 1u)) >> 16);
}

#define MFMA16(a,b,c) __builtin_amdgcn_mfma_f32_16x16x32_bf16((a),(b),(c),0,0,0)

// async global->LDS, 16B per lane (emits global_load_lds_dwordx4)
typedef const __attribute__((address_space(1))) char glb_c;
typedef __attribute__((address_space(3))) char lds_c;
static __device__ __forceinline__ void gload_lds16(const void* g, void* l){
  __builtin_amdgcn_global_load_lds((glb_c*)g, (lds_c*)l, 16, 0, 0);
}

// Model dims
#define SEQN   2048
#define PROJD  8512
#define CONVD  4352
#define INTERD 4096
#define NST    128
#define QC     64
#define NCHUNK 32

// ---------------------------------------------------------------------------
// Input dtype detection (fp32 confirmed; kept for robustness).
__global__ __launch_bounds__(256) void detect_kernel(
    const void* __restrict__ hidden, u32* __restrict__ flag)
{
  __shared__ int cnt;
  if (threadIdx.x == 0) cnt = 0;
  __syncthreads();
  if (threadIdx.x < 128){
    u16 v = ((const u16*)hidden)[threadIdx.x * 2];
    int e = (v >> 7) & 0xFF;
    int plaus = (v == 0) || (e >= 0x70 && e <= 0x8F);
    atomicAdd(&cnt, plaus);
  }
  __syncthreads();
  if (threadIdx.x == 0) *flag = (cnt < 64) ? 1u : 0u;   // 1 = fp32 inputs
}

// Vectorized convert: 4 elems/thread (float4 in -> short4 out). n % 4 == 0.
__global__ __launch_bounds__(256) void cvt_kernel(
    const void* __restrict__ src, u16* __restrict__ dst, int n,
    const u32* __restrict__ flag)
{
  bool isf32 = (*flag != 0);
  int n4 = n >> 2;
  int stride = gridDim.x * 256;
  for (int i = blockIdx.x*256 + threadIdx.x; i < n4; i += stride){
    s16x4 o;
    if (isf32){
      f32x4 v = ((const f32x4*)src)[i];
      #pragma unroll
      for (int e = 0; e < 4; e++) o[e] = (short)f2bf(v[e]);
    } else {
      o = ((const s16x4*)src)[i];
    }
    ((s16x4*)dst)[i] = o;
  }
}

// Convert + transpose weights: src [K][N] (fp32 or bf16) -> dst [Npad][K] bf16.
// Rows n >= N are zero-filled (pad for tile-exact GEMM).
__global__ __launch_bounds__(256) void cvt_transpose_kernel(
    const void* __restrict__ src, u16* __restrict__ dst,
    int K, int N, int Npad, const u32* __restrict__ flag)
{
  bool isf32 = (*flag != 0);
  __shared__ u16 tile[64][72];
  int n0 = blockIdx.x * 64, k0 = blockIdx.y * 64;
  int tid = threadIdx.x;
  int tr = tid >> 6;     // wave id 0..3
  int tc = tid & 63;
  #pragma unroll
  for (int i = 0; i < 16; i++){
    int k = i*4 + tr;
    int gk = k0 + k, gn = n0 + tc;
    float v = 0.f;
    if (gk < K && gn < N)
      v = isf32 ? ((const float*)src)[(size_t)gk*N + gn]
                : bf2f(((const u16*)src)[(size_t)gk*N + gn]);
    tile[k][tc] = f2bf(v);
  }
  __syncthreads();
  #pragma unroll
  for (int i = 0; i < 16; i++){
    int n = i*4 + tr;
    int gn = n0 + n;
    if (gn < Npad && (k0 + tc) < K)
      dst[(size_t)gn*K + k0 + tc] = tile[tc][n];
  }
}

__global__ __launch_bounds__(256) void cvt_small_kernel(
    const void* cw, const void* cb, const void* al, const void* dv,
    const void* db, const void* nw, u16* __restrict__ base,
    const u32* __restrict__ flag)
{
  bool isf32 = (*flag != 0);
  int idx = blockIdx.x*256 + threadIdx.x;   // 0 .. 26047
  if (idx >= 26048) return;
  const void* src; int off;
  if      (idx < 17408){ src = cw; off = idx;          }
  else if (idx < 21760){ src = cb; off = idx - 17408;  }
  else if (idx < 21824){ src = al; off = idx - 21760;  }
  else if (idx < 21888){ src = dv; off = idx - 21824;  }
  else if (idx < 21952){ src = db; off = idx - 21888;  }
  else                 { src = nw; off = idx - 21952;  }
  u16 v = isf32 ? f2bf(((const float*)src)[off]) : ((const u16*)src)[off];
  base[idx] = v;
}

// ---------------------------------------------------------------------------
// C = A[M,K] @ Bt[N,K]^T (row-major bf16, B pre-transposed), fp32 MFMA accum.
// Tile (MT*128)x256, BK=64, 512 threads (8 waves, 2Mx4N), LDS double-buffer,
// 8-phase counted-vmcnt, ONE barrier per phase.
//
// MT=2 (balanced reads, RACE-FREE stage plan; r5's p2/p6 same-window
// B-read/B-stage collision removed):
//   phase (kk=(p>>1)&1, h=p&1): read 4 A-frags (mf-half h, kk);
//   +4 B-frags at h==0. B buf0 reads end p2, A buf0 end p3, B buf1 end p6,
//   A buf1 end p7 -> stages: p0:A1h0 p1:A1h1 p3:B0h0+vmcnt(2) p4:B0h1
//   p5:A0h0 p6:A0h1 p7:B1h0+B1h1+vmcnt(4). Every stage >=1 barrier after
//   its region's last read; no phase reads a region staged in its window.
//   Ledger: enter 4 (B odd); p3 gate leaves 2 (B0h0), p7 gate leaves 4 (B T3).
// MT=1: r4-proven quadrant schedule (reads A-quad q + all B at q==0;
//   stages p0..p7 A1h0,A1h1,B0h0,B0h1+vmcnt(4),A0h0,A0h1,B1h0,B1h1+vmcnt(4)).
// Last iter: vmcnt(0) at p3, no stages after.
// Requires: M%(MT*128)==0, N%256==0 (pad), K%128==0, nwg%8==0.
template<int MT>
__global__ __launch_bounds__(512, 2) void gemm_kernel(
    const u16* __restrict__ A, const u16* __restrict__ Bt,
    u16* __restrict__ C0, u16* __restrict__ C1, u16* __restrict__ C2,
    float* __restrict__ CF,
    int M, int N, int K, int mode)
{
  constexpr int ASZ  = MT * 16384;        // A bytes per buffer
  constexpr int BUFS = ASZ + 32768;       // buffer stride in bytes (A|B)
  __shared__ u16 smem[BUFS];              // u16 count = 2 buffers of BUFS bytes

  const int nbx = gridDim.x;
  const int nwg = nbx * gridDim.y;
  const int bid = blockIdx.y * nbx + blockIdx.x;
  const int swz = (bid & 7) * (nwg >> 3) + (bid >> 3);
  const int m0 = (swz / nbx) * (MT*128), n0 = (swz % nbx) * 256;

  const int tid = threadIdx.x;
  const int wave = tid >> 6, lane = tid & 63;
  const int l15 = lane & 15, quad = lane >> 4;
  const int wm = wave >> 2, wn = wave & 3;   // 2 x 4 wave grid

  // staging: thread covers row (tid>>3) of each 64-row group, chunk (tid&7);
  // global source chunk XOR-swizzled, LDS write linear (both-sides rule).
  const size_t Kb = (size_t)K * 2;
  const int srow = tid >> 3;
  const int schk = (tid & 7) ^ (srow & 7);
  const char* Abp = (const char*)A  + (size_t)(m0 + srow) * Kb + schk * 16;
  const char* Bbp = (const char*)Bt + (size_t)(n0 + srow) * Kb + schk * 16;
  char* ldsb = (char*)smem + wave * 1024;   // wave-uniform; HW adds lane*16

  // ds_read bases per [buffer][kk]; fragment row offset folds to immediate.
  const int aoff0 = ((quad    ) ^ (l15 & 7)) << 4;
  const int aoff1 = ((quad + 4) ^ (l15 & 7)) << 4;
  const char* ardb[2][2];
  const char* brdb[2][2];
  #pragma unroll
  for (int c = 0; c < 2; c++){
    ardb[c][0] = (const char*)smem + c*BUFS + (wm*(MT*64) + l15)*128 + aoff0;
    ardb[c][1] = (const char*)smem + c*BUFS + (wm*(MT*64) + l15)*128 + aoff1;
    brdb[c][0] = (const char*)smem + c*BUFS + ASZ + (wn*64 + l15)*128 + aoff0;
    brdb[c][1] = (const char*)smem + c*BUFS + ASZ + (wn*64 + l15)*128 + aoff1;
  }

  f32x4 acc[MT*4][4];
  #pragma unroll
  for (int i = 0; i < MT*4; i++)
    #pragma unroll
    for (int j = 0; j < 4; j++) acc[i][j] = (f32x4){0.f,0.f,0.f,0.f};

  bf16x8 af[4];    // MT=2: 4 A-frags/phase; MT=1: af[0..1]
  bf16x8 bfr[8];   // MT=2: bfr[0..3]; MT=1: 8 frags read at q==0

#define STGB(par, h, kt) do{                                             \
    const char* _s = Bbp + (size_t)((h)*128)*Kb + (size_t)(kt)*128;      \
    char* _d = ldsb + (par)*BUFS + ASZ + (h)*16384;                      \
    gload_lds16(_s, _d);                                                 \
    gload_lds16(_s + 64*Kb, _d + 8192);                                  \
  }while(0)
#define STGA(par, h, kt) do{                                             \
    const char* _s = Abp + (size_t)((h)*(MT*64))*Kb + (size_t)(kt)*128;  \
    char* _d = ldsb + (par)*BUFS + (h)*(MT*8192);                        \
    gload_lds16(_s, _d);                                                 \
    if (MT == 2) gload_lds16(_s + 64*Kb, _d + 8192);                     \
  }while(0)

  // ---- prologue: stage T0 fully + B(T1); keep B(T1) in flight
  STGB(0,0,0); STGB(0,1,0);
  STGA(0,0,0); STGA(0,1,0);
  STGB(1,0,1); STGB(1,1,1);
  asm volatile("s_waitcnt vmcnt(4)" ::: "memory");
  __builtin_amdgcn_s_barrier();

  const int NT = K >> 6;
  for (int I = 0; I < (NT >> 1); ++I){
    const int T1 = 2*I+1, T2 = 2*I+2, T3 = 2*I+3;
    const bool pf = (T2 < NT);
    #pragma unroll
    for (int p = 0; p < 8; ++p){
      const int c = p >> 2;   // buffer/tile parity
      // 1) ds_reads for THIS phase
      if (MT == 2){
        const int kk = (p >> 1) & 1, h = p & 1;
        #pragma unroll
        for (int mf2 = 0; mf2 < 4; ++mf2)
          af[mf2] = *(const bf16x8*)(ardb[c][kk] + (h*4+mf2)*2048);
        if (h == 0){
          #pragma unroll
          for (int nf = 0; nf < 4; ++nf)
            bfr[nf] = *(const bf16x8*)(brdb[c][kk] + nf*2048);
        }
      } else {
        const int q = p & 3;
        af[0] = *(const bf16x8*)(ardb[c][0] + q*2048);
        af[1] = *(const bf16x8*)(ardb[c][1] + q*2048);
        if (q == 0){
          #pragma unroll
          for (int nf = 0; nf < 4; ++nf){
            bfr[nf*2+0] = *(const bf16x8*)(brdb[c][0] + nf*2048);
            bfr[nf*2+1] = *(const bf16x8*)(brdb[c][1] + nf*2048);
          }
        }
      }
      // 2) stage half-tiles + counted vmcnt gates (plans differ per MT)
      if (MT == 2){
        if      (p == 0) STGA(1,0,T1);
        else if (p == 1) STGA(1,1,T1);
        else if (p == 3){
          if (pf){ STGB(0,0,T2);
                   asm volatile("s_waitcnt vmcnt(2)" ::: "memory"); }
          else     asm volatile("s_waitcnt vmcnt(0)" ::: "memory");
        }
        else if (p == 4){ if (pf) STGB(0,1,T2); }
        else if (p == 5){ if (pf) STGA(0,0,T2); }
        else if (p == 6){ if (pf) STGA(0,1,T2); }
        else if (p == 7){ if (pf){ STGB(1,0,T3); STGB(1,1,T3);
                   asm volatile("s_waitcnt vmcnt(4)" ::: "memory"); } }
      } else {
        if      (p == 0) STGA(1,0,T1);
        else if (p == 1) STGA(1,1,T1);
        else if (p == 2){ if (pf) STGB(0,0,T2); }
        else if (p == 3){
          if (pf){ STGB(0,1,T2);
                   asm volatile("s_waitcnt vmcnt(4)" ::: "memory"); }
          else     asm volatile("s_waitcnt vmcnt(0)" ::: "memory");
        }
        else if (p == 4){ if (pf) STGA(0,0,T2); }
        else if (p == 5){ if (pf) STGA(0,1,T2); }
        else if (p == 6){ if (pf) STGB(1,0,T3); }
        else            { if (pf){ STGB(1,1,T3);
                   asm volatile("s_waitcnt vmcnt(4)" ::: "memory"); } }
      }
      asm volatile("" ::: "memory");
      __builtin_amdgcn_s_barrier();
      // 3) MFMA (compiler inserts counted lgkmcnt; no post-MFMA barrier)
      __builtin_amdgcn_s_setprio(1);
      if (MT == 2){
        const int h = p & 1;
        #pragma unroll
        for (int mf2 = 0; mf2 < 4; ++mf2)
          #pragma unroll
          for (int nf = 0; nf < 4; ++nf)
            acc[h*4+mf2][nf] = MFMA16(af[mf2], bfr[nf], acc[h*4+mf2][nf]);
      } else {
        const int q = p & 3;
        #pragma unroll
        for (int nf = 0; nf < 4; ++nf){
          acc[q][nf] = MFMA16(af[0], bfr[nf*2+0], acc[q][nf]);
          acc[q][nf] = MFMA16(af[1], bfr[nf*2+1], acc[q][nf]);
        }
      }
      __builtin_amdgcn_s_setprio(0);
    }
  }
#undef STGA
#undef STGB

  // ---- epilogue
  #pragma unroll
  for (int nf = 0; nf < 4; nf++){
    int col = n0 + wn*64 + nf*16 + l15;
    #pragma unroll
    for (int mf = 0; mf < MT*4; mf++){
      #pragma unroll
      for (int r = 0; r < 4; r++){
        int row = m0 + wm*(MT*64) + mf*16 + quad*4 + r;
        float fv = acc[mf][nf][r];
        if (mode == 2){
          if (col < N) CF[(size_t)row*N + col] = fv;
        } else if (mode == 0){
          if (col < N) C0[(size_t)row*N + col] = f2bf(fv);
        } else {
          u16 v = f2bf(fv);
          if      (col < 4096) C0[(size_t)row*4096 + col] = v;
          else if (col < 8448) C1[(size_t)row*CONVD + (col - 4096)] = v;
          else if (col < 8512) C2[(size_t)row*64 + (col - 8448)] = v;
          // cols 8512..8703 are zero-padding, dropped
        }
      }
    }
  }
}

// ---------------------------------------------------------------------------
// Causal depthwise conv (K=4, left pad 3) + bias + silu; 0.5 mup folded.
// Vectorized: 8 channels/thread, 16B loads/stores (G13).
__global__ __launch_bounds__(256) void conv_silu_kernel(
    const u16* __restrict__ xbcr, const u16* __restrict__ conv_w,
    const u16* __restrict__ conv_b, u16* __restrict__ xbc)
{
  int c8 = blockIdx.x * 256 + threadIdx.x;   // channel octet, 544 active
  if (c8 >= 544) return;
  int c = c8 * 8;
  int rl = blockIdx.y;
  int b = rl >> 11, l = rl & 2047;

  u16 wv[32];
  *(u32x4*)(wv +  0) = *(const u32x4*)(conv_w + c*4);
  *(u32x4*)(wv +  8) = *(const u32x4*)(conv_w + c*4 +  8);
  *(u32x4*)(wv + 16) = *(const u32x4*)(conv_w + c*4 + 16);
  *(u32x4*)(wv + 24) = *(const u32x4*)(conv_w + c*4 + 24);
  u16 bv[8];
  *(u32x4*)bv = *(const u32x4*)(conv_b + c);

  u16 xv[4][8];
  #pragma unroll
  for (int k = 0; k < 4; k++){
    int s = l + k - 3;
    if (s >= 0)
      *(u32x4*)(xv[k]) = *(const u32x4*)(xbcr + (size_t)(b*2048 + s)*CONVD + c);
    else
      *(u32x4*)(xv[k]) = (u32x4){0,0,0,0};
  }
  u16 ov[8];
  #pragma unroll
  for (int e = 0; e < 8; e++){
    float acc = bf2f(bv[e]);
    #pragma unroll
    for (int k = 0; k < 4; k++)
      acc += bf2f(xv[k][e]) * (0.5f * bf2f(wv[e*4 + k]));
    float sig = 1.f / (1.f + __expf(-acc));
    ov[e] = f2bf(acc * sig);
  }
  *(u32x4*)(xbc + (size_t)rl*CONVD + c) = *(u32x4*)ov;
}

// ---------------------------------------------------------------------------
// dt_soft = softplus(dtraw + dt_bias); ldA = dt_soft * (-exp(A_log)).
__global__ __launch_bounds__(256) void dt_kernel(
    const u16* __restrict__ dtraw, const u16* __restrict__ dt_bias,
    const u16* __restrict__ A_log, float* __restrict__ dt_soft,
    float* __restrict__ ldA)
{
  int idx = blockIdx.x * 256 + threadIdx.x;  // 4096*64
  int h = idx & 63;
  float x = bf2f(dtraw[idx]) + bf2f(dt_bias[h]);
  float sp = (x > 20.f) ? x : log1pf(expf(x));
  float A = -expf(bf2f(A_log[h]));
  dt_soft[idx] = sp;
  ldA[idx] = sp * A;
}

__global__ __launch_bounds__(256) void chunk_decay_kernel(
    const float* __restrict__ ldA, float* __restrict__ cdexp)
{
  int idx = blockIdx.x * 256 + threadIdx.x;  // 4096
  int q = idx & 31, bh = idx >> 5;
  int b = bh >> 6, h = bh & 63;
  float s = 0.f;
  int t0 = q * QC;
  for (int t = 0; t < QC; t++) s += ldA[(size_t)(b*2048 + t0 + t)*64 + h];
  cdexp[idx] = expf(s);
}

// ---------------------------------------------------------------------------
// SSD intra-chunk (validated in r4 bisection: matches exact scan).
#define SBS  136
#define SUTS 80
#define SMS  80
__global__ __launch_bounds__(256) void ssd_intra_kernel(
    const u16* __restrict__ xbc, const float* __restrict__ dt_soft,
    const float* __restrict__ ldA, u16* __restrict__ S,
    u16* __restrict__ y)
{
  int q = blockIdx.x, h = blockIdx.y, b = blockIdx.z;
  int bh = b*64 + h;
  int t0 = q * QC;
  int tid = threadIdx.x, wave = tid >> 6, lane = tid & 63;
  int l15 = lane & 15, quad = lane >> 4;

  __shared__ u16 sB [64*SBS];
  __shared__ u16 sCM[64*SBS];
  __shared__ u16 sBt[128*64];
  __shared__ u16 sUt[64*SUTS];
  __shared__ float sLa[64];
  __shared__ float sW[64];

  if (tid < 64){
    float v = ldA[(size_t)(b*2048 + t0 + tid)*64 + h];
    #pragma unroll
    for (int off = 1; off < 64; off <<= 1){
      float o = __shfl_up(v, off, 64);
      if (lane >= off) v += o;
    }
    sLa[tid] = v;
  }
  __syncthreads();
  float laE = sLa[63];
  if (tid < 64) sW[tid] = __expf(laE - sLa[tid]);
  __syncthreads();

  #pragma unroll
  for (int i = 0; i < 4; i++){
    int ch = i*256 + tid;
    int s = ch >> 4, nc = (ch & 15) * 8;
    const u16* src = xbc + (size_t)(b*2048 + t0 + s)*CONVD;
    u32x4 vb = *(const u32x4*)(src + 4096 + nc);
    u32x4 vc = *(const u32x4*)(src + 4224 + nc);
    *(u32x4*)(sB  + s*SBS + nc) = vb;
    *(u32x4*)(sCM + s*SBS + nc) = vc;
    float wdec = sW[s];
    const u16* pb = (const u16*)&vb;
    #pragma unroll
    for (int e = 0; e < 8; e++)
      sBt[(nc + e)*64 + s] = f2bf(bf2f(pb[e]) * wdec);
  }
  #pragma unroll
  for (int i = 0; i < 2; i++){
    int ch = i*256 + tid;
    int s = ch >> 3, pc = (ch & 7) * 8;
    const u16* src = xbc + (size_t)(b*2048 + t0 + s)*CONVD + h*64 + pc;
    u32x4 vx = *(const u32x4*)src;
    float dt = dt_soft[(size_t)(b*2048 + t0 + s)*64 + h];
    const u16* px = (const u16*)&vx;
    #pragma unroll
    for (int e = 0; e < 8; e++)
      sUt[(pc + e)*SUTS + s] = f2bf(bf2f(px[e]) * dt);
  }
  __syncthreads();

  // MFMA1: M[t][s] = sum_n C[t][n]*B[s][n]
  int tr = (wave & 1)*32, sc = (wave >> 1)*32;
  f32x4 aM[2][2];
  #pragma unroll
  for (int i=0;i<2;i++)
    #pragma unroll
    for (int j=0;j<2;j++) aM[i][j] = (f32x4){0.f,0.f,0.f,0.f};
  #pragma unroll
  for (int kk = 0; kk < 128; kk += 32){
    bf16x8 a0 = *(const bf16x8*)(sCM + (tr      + l15)*SBS + kk + quad*8);
    bf16x8 a1 = *(const bf16x8*)(sCM + (tr + 16 + l15)*SBS + kk + quad*8);
    bf16x8 b0 = *(const bf16x8*)(sB  + (sc      + l15)*SBS + kk + quad*8);
    bf16x8 b1 = *(const bf16x8*)(sB  + (sc + 16 + l15)*SBS + kk + quad*8);
    aM[0][0] = MFMA16(a0, b0, aM[0][0]);
    aM[0][1] = MFMA16(a0, b1, aM[0][1]);
    aM[1][0] = MFMA16(a1, b0, aM[1][0]);
    aM[1][1] = MFMA16(a1, b1, aM[1][1]);
  }
  __syncthreads();
  u16* sM = sCM;
  #pragma unroll
  for (int i = 0; i < 2; i++){
    #pragma unroll
    for (int j = 0; j < 2; j++){
      int scol = sc + j*16 + l15;
      #pragma unroll
      for (int r = 0; r < 4; r++){
        int trow = tr + i*16 + quad*4 + r;
        float v = 0.f;
        if (scol <= trow) v = aM[i][j][r] * __expf(sLa[trow] - sLa[scol]);
        sM[trow*SMS + scol] = f2bf(v);
      }
    }
  }
  __syncthreads();

  // MFMA2: Y[t][p] = sum_s M[t][s]*u[s][p]
  f32x4 aY[2][2];
  #pragma unroll
  for (int i=0;i<2;i++)
    #pragma unroll
    for (int j=0;j<2;j++) aY[i][j] = (f32x4){0.f,0.f,0.f,0.f};
  #pragma unroll
  for (int kk = 0; kk < 64; kk += 32){
    bf16x8 a0 = *(const bf16x8*)(sM  + (tr      + l15)*SMS  + kk + quad*8);
    bf16x8 a1 = *(const bf16x8*)(sM  + (tr + 16 + l15)*SMS  + kk + quad*8);
    bf16x8 b0 = *(const bf16x8*)(sUt + (sc      + l15)*SUTS + kk + quad*8);
    bf16x8 b1 = *(const bf16x8*)(sUt + (sc + 16 + l15)*SUTS + kk + quad*8);
    aY[0][0] = MFMA16(a0, b0, aY[0][0]);
    aY[0][1] = MFMA16(a0, b1, aY[0][1]);
    aY[1][0] = MFMA16(a1, b0, aY[1][0]);
    aY[1][1] = MFMA16(a1, b1, aY[1][1]);
  }
  #pragma unroll
  for (int i = 0; i < 2; i++){
    #pragma unroll
    for (int j = 0; j < 2; j++){
      int p = sc + j*16 + l15;
      #pragma unroll
      for (int r = 0; r < 4; r++){
        int t = tr + i*16 + quad*4 + r;
        y[(size_t)(b*2048 + t0 + t)*INTERD + h*64 + p] = f2bf(aY[i][j][r]);
      }
    }
  }

  // MFMA3: S[p][n] = sum_s u[s][p]*decay(s)*B[s][n]
  int pr = (wave & 1)*32, nw = (wave >> 1)*64;
  f32x4 aS[2][4];
  #pragma unroll
  for (int i=0;i<2;i++)
    #pragma unroll
    for (int j=0;j<4;j++) aS[i][j] = (f32x4){0.f,0.f,0.f,0.f};
  #pragma unroll
  for (int kk = 0; kk < 64; kk += 32){
    bf16x8 a0 = *(const bf16x8*)(sUt + (pr      + l15)*SUTS + kk + quad*8);
    bf16x8 a1 = *(const bf16x8*)(sUt + (pr + 16 + l15)*SUTS + kk + quad*8);
    #pragma unroll
    for (int j = 0; j < 4; j++){
      bf16x8 bb = *(const bf16x8*)(sBt + (nw + j*16 + l15)*64 + kk + quad*8);
      aS[0][j] = MFMA16(a0, bb, aS[0][j]);
      aS[1][j] = MFMA16(a1, bb, aS[1][j]);
    }
  }
  u16* Sl = S + ((size_t)bh*NCHUNK + q)*8192;
  #pragma unroll
  for (int i = 0; i < 2; i++){
    #pragma unroll
    for (int j = 0; j < 4; j++){
      int n = nw + j*16 + l15;
      #pragma unroll
      for (int r = 0; r < 4; r++){
        int p = pr + i*16 + quad*4 + r;
        Sl[p*NST + n] = f2bf(aS[i][j][r]);
      }
    }
  }
}

// ---------------------------------------------------------------------------
// Inter-chunk recurrence, in-place.
__global__ __launch_bounds__(256) void ssd_carry_kernel(
    u16* __restrict__ S, const float* __restrict__ cdexp)
{
  int idx = blockIdx.x * 256 + threadIdx.x;   // 2*64*8192
  int e = idx & 8191, bh = idx >> 13;
  float E = 0.f;
  for (int q = 0; q < NCHUNK; q++){
    size_t off = ((size_t)bh*NCHUNK + q)*8192 + e;
    float v = bf2f(S[off]);
    S[off] = f2bf(E);
    E = cdexp[bh*NCHUNK + q] * E + v;
  }
}

// ---------------------------------------------------------------------------
// Inter-chunk output: y += exp(la[t]) * C_t @ S_q^T + D*x
__global__ __launch_bounds__(256) void ssd_inter_kernel(
    const u16* __restrict__ xbc, const float* __restrict__ ldA,
    const u16* __restrict__ S, const u16* __restrict__ Dvec,
    u16* __restrict__ y)
{
  int q = blockIdx.x, h = blockIdx.y, b = blockIdx.z;
  int bh = b*64 + h;
  int t0 = q * QC;
  int tid = threadIdx.x, wave = tid >> 6, lane = tid & 63;
  int l15 = lane & 15, quad = lane >> 4;

  __shared__ u16 sC[64*SBS];
  __shared__ u16 sS[64*SBS];
  __shared__ float sLa[64];

  if (tid < 64){
    float v = ldA[(size_t)(b*2048 + t0 + tid)*64 + h];
    #pragma unroll
    for (int off = 1; off < 64; off <<= 1){
      float o = __shfl_up(v, off, 64);
      if (lane >= off) v += o;
    }
    sLa[tid] = v;
  }
  const u16* Sc = S + ((size_t)bh*NCHUNK + q)*8192;
  #pragma unroll
  for (int i = 0; i < 4; i++){
    int ch = i*256 + tid;
    int s = ch >> 4, nc = (ch & 15) * 8;
    *(u32x4*)(sC + s*SBS + nc) =
        *(const u32x4*)(xbc + (size_t)(b*2048 + t0 + s)*CONVD + 4224 + nc);
    *(u32x4*)(sS + s*SBS + nc) = *(const u32x4*)(Sc + s*NST + nc);
  }
  __syncthreads();

  int tr = (wave & 1)*32, pc = (wave >> 1)*32;
  f32x4 acc[2][2];
  #pragma unroll
  for (int i=0;i<2;i++)
    #pragma unroll
    for (int j=0;j<2;j++) acc[i][j] = (f32x4){0.f,0.f,0.f,0.f};
  #pragma unroll
  for (int kk = 0; kk < 128; kk += 32){
    bf16x8 a0 = *(const bf16x8*)(sC + (tr      + l15)*SBS + kk + quad*8);
    bf16x8 a1 = *(const bf16x8*)(sC + (tr + 16 + l15)*SBS + kk + quad*8);
    bf16x8 b0 = *(const bf16x8*)(sS + (pc      + l15)*SBS + kk + quad*8);
    bf16x8 b1 = *(const bf16x8*)(sS + (pc + 16 + l15)*SBS + kk + quad*8);
    acc[0][0] = MFMA16(a0, b0, acc[0][0]);
    acc[0][1] = MFMA16(a0, b1, acc[0][1]);
    acc[1][0] = MFMA16(a1, b0, acc[1][0]);
    acc[1][1] = MFMA16(a1, b1, acc[1][1]);
  }
  float Dh = bf2f(Dvec[h]);
  #pragma unroll
  for (int i = 0; i < 2; i++){
    #pragma unroll
    for (int j = 0; j < 2; j++){
      int p = pc + j*16 + l15;
      #pragma unroll
      for (int r = 0; r < 4; r++){
        int t = tr + i*16 + quad*4 + r;
        size_t row = (size_t)(b*2048 + t0 + t);
        size_t yo = row*INTERD + h*64 + p;
        float xv = bf2f(xbc[row*CONVD + h*64 + p]);
        float v = bf2f(y[yo]) + __expf(sLa[t]) * acc[i][j][r] + Dh * xv;
        y[yo] = f2bf(v);
      }
    }
  }
}

// ---------------------------------------------------------------------------
// RMSNorm * norm_w, gated by silu(0.25*z). Vectorized 16B loads (G13).
__global__ __launch_bounds__(256) void rmsnorm_gate_kernel(
    const u16* __restrict__ y, const u16* __restrict__ z,
    const u16* __restrict__ norm_w, u16* __restrict__ g)
{
  int rl = blockIdx.x;
  int tid = threadIdx.x, wave = tid >> 6, lane = tid & 63;
  const u16* yr = y + (size_t)rl*INTERD;
  u16 vy[16];
  *(u32x4*)(vy + 0) = *(const u32x4*)(yr + tid*8);
  *(u32x4*)(vy + 8) = *(const u32x4*)(yr + 2048 + tid*8);
  float fy[16];
  float ss = 0.f;
  #pragma unroll
  for (int i = 0; i < 16; i++){
    float v = bf2f(vy[i]);
    fy[i] = v;
    ss += v*v;
  }
  #pragma unroll
  for (int off = 32; off >= 1; off >>= 1) ss += __shfl_xor(ss, off, 64);
  __shared__ float red[4];
  if (lane == 0) red[wave] = ss;
  __syncthreads();
  float tot = red[0] + red[1] + red[2] + red[3];
  float rstd = rsqrtf(tot * (1.f/4096.f) + 1e-5f);
  const u16* zr = z + (size_t)rl*INTERD;
  u16* gr = g + (size_t)rl*INTERD;
  u16 vz[16], vw[16], go[16];
  *(u32x4*)(vz + 0) = *(const u32x4*)(zr + tid*8);
  *(u32x4*)(vz + 8) = *(const u32x4*)(zr + 2048 + tid*8);
  *(u32x4*)(vw + 0) = *(const u32x4*)(norm_w + tid*8);
  *(u32x4*)(vw + 8) = *(const u32x4*)(norm_w + 2048 + tid*8);
  #pragma unroll
  for (int i = 0; i < 16; i++){
    float v = fy[i] * rstd * bf2f(vw[i]);
    float zv = 0.25f * bf2f(vz[i]);
    float sig = 1.f / (1.f + __expf(-zv));
    go[i] = f2bf(v * zv * sig);
  }
  *(u32x4*)(gr + tid*8)        = *(u32x4*)(go + 0);
  *(u32x4*)(gr + 2048 + tid*8) = *(u32x4*)(go + 8);
}

// ---------------------------------------------------------------------------
extern "C" void kernel_launch(void* const* d_in, const int* in_sizes, int n_in,
                              void* d_out, int out_size, void* d_ws, size_t ws_size,
                              hipStream_t stream)
{
  const void* hidden_r    = d_in[0];
  const void* in_proj_r   = d_in[1];
  const void* conv_w_r    = d_in[2];
  const void* conv_b_r    = d_in[3];
  const void* A_log_r     = d_in[4];
  const void* Dvec_r      = d_in[5];
  const void* dt_bias_r   = d_in[6];
  const void* norm_w_r    = d_in[7];
  const void* out_proj_r  = d_in[8];
  float* out = (float*)d_out;          // reference output dtype = float32
  char* ws = (char*)d_ws;

  // workspace layout (bytes); peak = 174,735,360 (proven in-bounds in r3)
  u16*   z     = (u16*)(ws + 0);               // 33,554,432
  u16*   xbcr  = (u16*)(ws + 33554432ull);     // 35,651,584 (dead after conv)
  u16*   yb    = (u16*)(ws + 33554432ull);     // 33,554,432 overlays xbcr
  u16*   dtraw = (u16*)(ws + 69206016ull);     //    524,288
  u16*   xbc   = (u16*)(ws + 69730304ull);     // 35,651,584 (dead after inter)
  u16*   w2b   = (u16*)(ws + 69730304ull);     // 16,777,216 overlays xbc (late)  [2048][4096] = out_proj^T
  float* dt_s  = (float*)(ws + 105381888ull);  //  1,048,576
  float* lda   = (float*)(ws + 106430464ull);  //  1,048,576
  float* cdexp = (float*)(ws + 107479040ull);  //     16,384
  u32*   flag  = (u32*)(ws + 107495424ull);    //        256
  u16*   svec  = (u16*)(ws + 107495680ull);    //     52,096 packed small vectors
  u16*   cw_b  = svec;                         // conv_w  17408
  u16*   cb_b  = svec + 17408;                 // conv_b   4352
  u16*   al_b  = svec + 21760;                 // A_log      64
  u16*   d_b   = svec + 21824;                 // D          64
  u16*   db_b  = svec + 21888;                 // dt_bias    64
  u16*   nw_b  = svec + 21952;                 // norm_w   4096
  u16*   S     = (u16*)(ws + 107626496ull);    // 67,108,864 -> end 174,735,360
  u16*   hb    = (u16*)(ws + 107626496ull);    // 16,777,216 overlays S (early)
  u16*   w1b   = (u16*)(ws + 124403712ull);    // 35,651,584 overlays S (early) [8704][2048] = in_proj^T padded -> end 160,055,296
  u16*   g     = (u16*)(ws + 107626496ull);    // 33,554,432 overlays S (late)

  // 0) dtype detect + canonicalize to bf16 (weights transposed for GEMM)
  detect_kernel<<<1, 256, 0, stream>>>(hidden_r, flag);
  cvt_kernel<<<4096, 256, 0, stream>>>(hidden_r, hb, 8388608, flag);
  cvt_transpose_kernel<<<dim3(136, 32), 256, 0, stream>>>(
      in_proj_r, w1b, 2048, 8512, 8704, flag);
  cvt_small_kernel<<<102, 256, 0, stream>>>(conv_w_r, conv_b_r, A_log_r,
      Dvec_r, dt_bias_r, norm_w_r, svec, flag);
  // 1) GEMM1: split epilogue -> z / xbcr / dtraw  (M=4096, Npad=8704, K=2048)
  gemm_kernel<2><<<dim3(34, 16), 512, 0, stream>>>(
      hb, w1b, z, xbcr, dtraw, (float*)nullptr, 4096, 8704, 2048, 1);
  // 2) conv + silu (0.5 mup folded), vectorized 8 chan/thread
  conv_silu_kernel<<<dim3(3, 4096), 256, 0, stream>>>(xbcr, cw_b, cb_b, xbc);
  // 3) dt softplus + log-decays
  dt_kernel<<<1024, 256, 0, stream>>>(dtraw, db_b, al_b, dt_s, lda);
  chunk_decay_kernel<<<16, 256, 0, stream>>>(lda, cdexp);
  // 4) SSD chunked scan (validated against exact scan in r4)
  ssd_intra_kernel<<<dim3(NCHUNK, 64, 2), 256, 0, stream>>>(xbc, dt_s, lda, S, yb);
  ssd_carry_kernel<<<4096, 256, 0, stream>>>(S, cdexp);
  ssd_inter_kernel<<<dim3(NCHUNK, 64, 2), 256, 0, stream>>>(xbc, lda, S, d_b, yb);
  // 5) late transpose-conversion of out_proj into xbc's slot (xbc dead after inter)
  cvt_transpose_kernel<<<dim3(32, 64), 256, 0, stream>>>(
      out_proj_r, w2b, 4096, 2048, 2048, flag);
  // 6) RMSNorm + silu(0.25*z) gate (g overlays S)
  rmsnorm_gate_kernel<<<4096, 256, 0, stream>>>(yb, z, nw_b, g);
  // 7) GEMM2: out = g @ out_proj  (M=4096, N=2048, K=4096) -> fp32 out
  //    MT=1 (128x256 tile): grid 8x32 = 256 blocks = exactly 1/CU.
  gemm_kernel<1><<<dim3(8, 32), 512, 0, stream>>>(
      g, w2b, (u16*)nullptr, (u16*)nullptr, (u16*)nullptr, out,
      4096, 2048, 4096, 2);
}